// Round 5
// baseline (529.788 us; speedup 1.0000x reference)
//
#include <hip/hip_runtime.h>
#include <hip/hip_bf16.h>

#define HD 64

typedef unsigned short u16;

__device__ __forceinline__ float lrelu(float x) { return x > 0.f ? x : 0.2f * x; }
__device__ __forceinline__ int clampi(int v, int maxv) {
    return v < 0 ? 0 : (v >= maxv ? maxv - 1 : v);
}
__device__ __forceinline__ float bf2f(u16 u) {
    return __uint_as_float(((unsigned int)u) << 16);
}
// round-to-nearest-even fp32 -> bf16 (bit-level; inputs are finite)
__device__ __forceinline__ u16 f2bf(float f) {
    unsigned int u = __float_as_uint(f);
    unsigned int lsb = (u >> 16) & 1u;
    u += 0x7fffu + lsb;
    return (u16)(u >> 16);
}

// ---------------- init (zero deg/cursor/pooled) + node embedding fused ----------------
__global__ void k_init(const float* __restrict__ x, const float* __restrict__ W,
                       const float* __restrict__ b, float* __restrict__ h,
                       int* deg, int* cursor, float* pooled, int N, int B) {
    int i = blockIdx.x * blockDim.x + threadIdx.x;
    if (i < N) { deg[i] = 0; cursor[i] = 0; }
    if (i < B * HD) pooled[i] = 0.f;
    if (i < N * HD) {
        int n = i >> 6, c = i & 63;
        float acc = b[c];
        acc = fmaf(x[n * 3 + 0], W[0 * HD + c], acc);
        acc = fmaf(x[n * 3 + 1], W[1 * HD + c], acc);
        acc = fmaf(x[n * 3 + 2], W[2 * HD + c], acc);
        h[i] = fmaxf(acc, 0.f);
    }
}

// ---------------- degree histogram over dst ----------------
__global__ void k_deg(const int* __restrict__ dst, int* __restrict__ deg, int E, int N) {
    int e = blockIdx.x * blockDim.x + threadIdx.x;
    if (e < E) atomicAdd(&deg[clampi(dst[e], N)], 1);
}

// ---------------- hierarchical scan (2 kernels) ----------------
__global__ void k_scan1(const int* __restrict__ deg, int* __restrict__ tmp,
                        int* __restrict__ bsum, int N) {
    __shared__ int s[256];
    int tid = threadIdx.x;
    int i = blockIdx.x * 256 + tid;
    int v = (i < N) ? deg[i] : 0;
    s[tid] = v;
    __syncthreads();
    for (int off = 1; off < 256; off <<= 1) {
        int t = (tid >= off) ? s[tid - off] : 0;
        __syncthreads();
        s[tid] += t;
        __syncthreads();
    }
    if (i < N) tmp[i] = s[tid];
    if (tid == 255) bsum[blockIdx.x] = s[255];
}
// each block: wave 0 redundantly computes exclusive prefix of bsum[0..bid), then writes row_ptr
__global__ void k_scan23(const int* __restrict__ tmp, const int* __restrict__ bsum,
                         int* __restrict__ row_ptr, int N) {
    __shared__ int s_off;
    int t = threadIdx.x;
    if (t < 64) {
        int cnt = blockIdx.x;  // number of preceding blocks
        int v = 0;
        for (int base = 0; base < cnt; base += 64)
            if (base + t < cnt) v += bsum[base + t];
        #pragma unroll
        for (int o = 32; o > 0; o >>= 1) v += __shfl_xor(v, o);
        if (t == 0) s_off = v;
    }
    __syncthreads();
    int i = blockIdx.x * 256 + t;
    if (i == 0) row_ptr[0] = 0;
    if (i < N) row_ptr[i + 1] = tmp[i] + s_off;
}

// ---------------- CSR scatter; packed {src, eid} int2 per slot ----------------
__global__ void k_csr(const int* __restrict__ src, const int* __restrict__ dst,
                      const int* __restrict__ row_ptr, int* __restrict__ cursor,
                      int2* __restrict__ csr_se, int E, int N) {
    int e = blockIdx.x * blockDim.x + threadIdx.x;
    if (e >= E) return;
    int d = clampi(dst[e], N);
    int pos = row_ptr[d] + atomicAdd(&cursor[d], 1);
    if (pos < E) csr_se[pos] = make_int2(clampi(src[e], N), e);
}

// ---------------- ONCE: a_ed for all 3 layers x 4 heads, CSR order ----------------
// planar output: aed[l][(E+N)][4]
__global__ __launch_bounds__(256) void k_ee(
    const float* __restrict__ edge_attr, const float* __restrict__ eW,
    const float* __restrict__ eB, const float* __restrict__ lin_eW,
    const float* __restrict__ att_e, const int2* __restrict__ csr_se,
    float* __restrict__ aed, int E, int N) {
    __shared__ float s_ew[256];    // [k*64+d]
    __shared__ float s_eb[64];
    __shared__ float s_wred[768];  // [l*256 + h*64 + d]
    size_t P4 = (size_t)(E + N) * 4;
    int t = threadIdx.x;
    s_ew[t] = eW[t];
    if (t < 64) s_eb[t] = eB[t];
    for (int idx = t; idx < 768; idx += 256) {
        int l = idx >> 8, hd = idx & 255, hh = hd >> 6, d = hd & 63;
        const float* We = lin_eW + (size_t)l * HD * 256;
        const float* ae = att_e + (size_t)l * 256;
        float acc = 0.f;
        for (int c = 0; c < 64; c++)
            acc = fmaf(We[d * 256 + hh * 64 + c], ae[hh * 64 + c], acc);
        s_wred[idx] = acc;
    }
    __syncthreads();
    int j0 = (blockIdx.x * 256 + t) * 4;
    if (j0 >= E) return;
    float4 a[4];
    int nv = 0;
    #pragma unroll
    for (int q = 0; q < 4; q++) {
        int j = j0 + q;
        if (j < E) {
            a[q] = *(const float4*)(edge_attr + (size_t)csr_se[j].y * 4);
            nv = q + 1;
        } else {
            a[q] = make_float4(0.f, 0.f, 0.f, 0.f);
        }
    }
    float acc[4][12];
    #pragma unroll
    for (int q = 0; q < 4; q++)
        #pragma unroll
        for (int m = 0; m < 12; m++) acc[q][m] = 0.f;
    for (int k = 0; k < HD; k++) {
        float e0 = s_ew[k], e1 = s_ew[64 + k], e2 = s_ew[128 + k], e3 = s_ew[192 + k];
        float eb = s_eb[k];
        float w[12];
        #pragma unroll
        for (int m = 0; m < 12; m++)
            w[m] = s_wred[(m >> 2) * 256 + (m & 3) * 64 + k];
        #pragma unroll
        for (int q = 0; q < 4; q++) {
            float v = fmaf(a[q].x, e0, fmaf(a[q].y, e1,
                      fmaf(a[q].z, e2, fmaf(a[q].w, e3, eb))));
            v = fmaxf(v, 0.f);
            #pragma unroll
            for (int m = 0; m < 12; m++) acc[q][m] = fmaf(v, w[m], acc[q][m]);
        }
    }
    #pragma unroll
    for (int q = 0; q < 4; q++) {
        if (q >= nv) break;
        #pragma unroll
        for (int l = 0; l < 3; l++) {
            *(float4*)(aed + l * P4 + (size_t)(j0 + q) * 4) =
                make_float4(acc[q][l * 4 + 0], acc[q][l * 4 + 1],
                            acc[q][l * 4 + 2], acc[q][l * 4 + 3]);
        }
    }
}

// ---------------- ONCE: self-loop a_ed rows by LINEARITY ----------------
__global__ void k_selfed(const int* __restrict__ row_ptr, float* __restrict__ aed,
                         int E, int N) {
    int n = blockIdx.x * blockDim.x + threadIdx.x;
    if (n >= N) return;
    size_t P4 = (size_t)(E + N) * 4;
    int r0 = row_ptr[n], r1 = row_ptr[n + 1];
    float acc[12];
    #pragma unroll
    for (int m = 0; m < 12; m++) acc[m] = 0.f;
    for (int j = r0; j < r1; j++) {
        #pragma unroll
        for (int l = 0; l < 3; l++) {
            float4 v = *(const float4*)(aed + l * P4 + (size_t)j * 4);
            acc[l * 4 + 0] += v.x; acc[l * 4 + 1] += v.y;
            acc[l * 4 + 2] += v.z; acc[l * 4 + 3] += v.w;
        }
    }
    float inv = 1.f / fmaxf((float)(r1 - r0), 1.f);
    #pragma unroll
    for (int l = 0; l < 3; l++) {
        *(float4*)(aed + l * P4 + (size_t)(E + n) * 4) =
            make_float4(acc[l * 4 + 0] * inv, acc[l * 4 + 1] * inv,
                        acc[l * 4 + 2] * inv, acc[l * 4 + 3] * inv);
    }
}

// ---------------- per-layer: xp = h@W, 8 nodes/block, broadcast h loads, NO LDS ----------
// All lanes of a wave read the same h line (L1 broadcast). NPB=8 keeps live VGPRs ~60
// (8 acc + 8x4 h + 4 W) -- the NPB=32 version spilled everything (VGPR_Count=28, 60us).
#define NPB 8
__global__ __launch_bounds__(256) void k_xp(
    const float* __restrict__ h, const float* __restrict__ W,
    const float* __restrict__ asrc, const float* __restrict__ adst,
    u16* __restrict__ xp, float* __restrict__ a_s, float* __restrict__ a_d, int N) {
    int n0 = blockIdx.x * NPB;
    int c = threadIdx.x;
    int nlim = N - n0;  // >= 1
    const float* hp = h + (size_t)n0 * HD;
    float acc[NPB];
    #pragma unroll
    for (int k = 0; k < NPB; k++) acc[k] = 0.f;
    for (int d = 0; d < HD; d += 4) {
        float w0 = W[(d + 0) * 256 + c];
        float w1 = W[(d + 1) * 256 + c];
        float w2 = W[(d + 2) * 256 + c];
        float w3 = W[(d + 3) * 256 + c];
        #pragma unroll
        for (int k = 0; k < NPB; k++) {
            int kk = (k < nlim) ? k : 0;  // clamp for tail block
            float4 hv = *(const float4*)(hp + kk * HD + d);
            acc[k] = fmaf(hv.x, w0, acc[k]);
            acc[k] = fmaf(hv.y, w1, acc[k]);
            acc[k] = fmaf(hv.z, w2, acc[k]);
            acc[k] = fmaf(hv.w, w3, acc[k]);
        }
    }
    float as_ = asrc[c], ad_ = adst[c];
    int hh = c >> 6, cc = c & 63;
    #pragma unroll
    for (int k = 0; k < NPB; k++) {
        int nn = n0 + k;
        if (nn >= N) break;  // wave-uniform
        float ps = acc[k] * as_;
        float pd = acc[k] * ad_;
        #pragma unroll
        for (int o = 32; o > 0; o >>= 1) {
            ps += __shfl_xor(ps, o);
            pd += __shfl_xor(pd, o);
        }
        xp[(size_t)nn * 256 + c] = f2bf(acc[k]);
        if (cc == 0) { a_s[nn * 4 + hh] = ps; a_d[nn * 4 + hh] = pd; }
    }
}

// ---------------- per-layer GAT aggregate with fused attention weights ----------------
// On the LAST layer (pooled != nullptr) also atomically accumulates h_out into
// pooled[batch[n]] -- removes the dedicated pooling pass (was 47us latency-bound).
__global__ __launch_bounds__(256) void k_gat(
    const u16* __restrict__ xp, const float* __restrict__ a_s,
    const float* __restrict__ a_d, const float* __restrict__ aedl,
    const int* __restrict__ row_ptr, const int2* __restrict__ csr_se,
    const float* __restrict__ convb, float* __restrict__ h_out,
    const int* __restrict__ batch, float* __restrict__ pooled, int N, int E) {
    int wave = threadIdx.x >> 6, lane = threadIdx.x & 63;
    int n = blockIdx.x * 4 + wave;
    if (n >= N) return;
    int g = lane >> 4, p = lane & 15;
    int r0 = row_ptr[n], r1 = row_ptr[n + 1];
    float4 ad4 = *(const float4*)(a_d + (size_t)n * 4);
    float a00 = 0.f, a01 = 0.f, a02 = 0.f, a03 = 0.f;
    float a10 = 0.f, a11 = 0.f, a12 = 0.f, a13 = 0.f;
    float a20 = 0.f, a21 = 0.f, a22 = 0.f, a23 = 0.f;
    float a30 = 0.f, a31 = 0.f, a32 = 0.f, a33 = 0.f;
    float d0 = 0.f, d1 = 0.f, d2 = 0.f, d3 = 0.f;
    if (g == 0) {
        // self loop: src = n
        float4 as4 = *(const float4*)(a_s + (size_t)n * 4);
        float4 p4 = *(const float4*)(aedl + (size_t)(E + n) * 4);
        float w0 = __expf(lrelu(as4.x + ad4.x + p4.x));
        float w1 = __expf(lrelu(as4.y + ad4.y + p4.y));
        float w2 = __expf(lrelu(as4.z + ad4.z + p4.z));
        float w3 = __expf(lrelu(as4.w + ad4.w + p4.w));
        const u16* row = xp + (size_t)n * 256 + p * 4;
        ushort4 v0 = *(const ushort4*)(row);
        ushort4 v1 = *(const ushort4*)(row + 64);
        ushort4 v2 = *(const ushort4*)(row + 128);
        ushort4 v3 = *(const ushort4*)(row + 192);
        d0 += w0; d1 += w1; d2 += w2; d3 += w3;
        a00 = fmaf(w0, bf2f(v0.x), a00); a01 = fmaf(w0, bf2f(v0.y), a01);
        a02 = fmaf(w0, bf2f(v0.z), a02); a03 = fmaf(w0, bf2f(v0.w), a03);
        a10 = fmaf(w1, bf2f(v1.x), a10); a11 = fmaf(w1, bf2f(v1.y), a11);
        a12 = fmaf(w1, bf2f(v1.z), a12); a13 = fmaf(w1, bf2f(v1.w), a13);
        a20 = fmaf(w2, bf2f(v2.x), a20); a21 = fmaf(w2, bf2f(v2.y), a21);
        a22 = fmaf(w2, bf2f(v2.z), a22); a23 = fmaf(w2, bf2f(v2.w), a23);
        a30 = fmaf(w3, bf2f(v3.x), a30); a31 = fmaf(w3, bf2f(v3.y), a31);
        a32 = fmaf(w3, bf2f(v3.z), a32); a33 = fmaf(w3, bf2f(v3.w), a33);
    }
    int j = r0 + g;
    int2 se = (j < r1) ? csr_se[j] : make_int2(0, 0);
    for (; j < r1; j += 4) {
        int jn = j + 4;
        int2 se_n = (jn < r1) ? csr_se[jn] : make_int2(0, 0);  // prefetch
        int s = se.x;
        float4 as4 = *(const float4*)(a_s + (size_t)s * 4);
        float4 p4 = *(const float4*)(aedl + (size_t)j * 4);
        float w0 = __expf(lrelu(as4.x + ad4.x + p4.x));
        float w1 = __expf(lrelu(as4.y + ad4.y + p4.y));
        float w2 = __expf(lrelu(as4.z + ad4.z + p4.z));
        float w3 = __expf(lrelu(as4.w + ad4.w + p4.w));
        const u16* row = xp + (size_t)s * 256 + p * 4;
        ushort4 v0 = *(const ushort4*)(row);
        ushort4 v1 = *(const ushort4*)(row + 64);
        ushort4 v2 = *(const ushort4*)(row + 128);
        ushort4 v3 = *(const ushort4*)(row + 192);
        d0 += w0; d1 += w1; d2 += w2; d3 += w3;
        a00 = fmaf(w0, bf2f(v0.x), a00); a01 = fmaf(w0, bf2f(v0.y), a01);
        a02 = fmaf(w0, bf2f(v0.z), a02); a03 = fmaf(w0, bf2f(v0.w), a03);
        a10 = fmaf(w1, bf2f(v1.x), a10); a11 = fmaf(w1, bf2f(v1.y), a11);
        a12 = fmaf(w1, bf2f(v1.z), a12); a13 = fmaf(w1, bf2f(v1.w), a13);
        a20 = fmaf(w2, bf2f(v2.x), a20); a21 = fmaf(w2, bf2f(v2.y), a21);
        a22 = fmaf(w2, bf2f(v2.z), a22); a23 = fmaf(w2, bf2f(v2.w), a23);
        a30 = fmaf(w3, bf2f(v3.x), a30); a31 = fmaf(w3, bf2f(v3.y), a31);
        a32 = fmaf(w3, bf2f(v3.z), a32); a33 = fmaf(w3, bf2f(v3.w), a33);
        se = se_n;
    }
    d0 += __shfl_xor(d0, 16); d0 += __shfl_xor(d0, 32);
    d1 += __shfl_xor(d1, 16); d1 += __shfl_xor(d1, 32);
    d2 += __shfl_xor(d2, 16); d2 += __shfl_xor(d2, 32);
    d3 += __shfl_xor(d3, 16); d3 += __shfl_xor(d3, 32);
    float i0 = 1.f / d0, i1 = 1.f / d1, i2 = 1.f / d2, i3 = 1.f / d3;
    float m0 = a00 * i0 + a10 * i1 + a20 * i2 + a30 * i3;
    float m1 = a01 * i0 + a11 * i1 + a21 * i2 + a31 * i3;
    float m2 = a02 * i0 + a12 * i1 + a22 * i2 + a32 * i3;
    float m3 = a03 * i0 + a13 * i1 + a23 * i2 + a33 * i3;
    m0 += __shfl_xor(m0, 16); m0 += __shfl_xor(m0, 32);
    m1 += __shfl_xor(m1, 16); m1 += __shfl_xor(m1, 32);
    m2 += __shfl_xor(m2, 16); m2 += __shfl_xor(m2, 32);
    m3 += __shfl_xor(m3, 16); m3 += __shfl_xor(m3, 32);
    if (lane < 16) {
        int c = p * 4;
        float o0 = fmaxf(0.25f * m0 + convb[c + 0], 0.f);
        float o1 = fmaxf(0.25f * m1 + convb[c + 1], 0.f);
        float o2 = fmaxf(0.25f * m2 + convb[c + 2], 0.f);
        float o3 = fmaxf(0.25f * m3 + convb[c + 3], 0.f);
        h_out[(size_t)n * HD + c + 0] = o0;
        h_out[(size_t)n * HD + c + 1] = o1;
        h_out[(size_t)n * HD + c + 2] = o2;
        h_out[(size_t)n * HD + c + 3] = o3;
        if (pooled != nullptr) {
            int bb = batch[n];
            atomicAdd(&pooled[bb * HD + c + 0], o0);
            atomicAdd(&pooled[bb * HD + c + 1], o1);
            atomicAdd(&pooled[bb * HD + c + 2], o2);
            atomicAdd(&pooled[bb * HD + c + 3], o3);
        }
    }
}

// ---------------- final MLP: B blocks x 64 threads; len via binary search ----------------
__global__ void k_mlp(const float* __restrict__ u, const float* __restrict__ gW,
                      const float* __restrict__ gb, const float* __restrict__ pooled,
                      const int* __restrict__ batch, const float* __restrict__ f1W,
                      const float* __restrict__ f1b, const float* __restrict__ f2W,
                      const float* __restrict__ f2b, float* __restrict__ out,
                      int N, int B) {
    __shared__ float z[2 * HD];
    __shared__ float z1s[HD];
    __shared__ int sb[2];
    int b = blockIdx.x, t = threadIdx.x;  // 64 threads
    if (t < 2) {
        int target = b + t;
        int lo = 0, hi = N;
        while (lo < hi) {
            int m = (lo + hi) >> 1;
            if (batch[m] < target) lo = m + 1; else hi = m;
        }
        sb[t] = lo;
    }
    float acc = gb[t];
    for (int k = 0; k < 10; k++) acc = fmaf(u[b * 10 + k], gW[k * HD + t], acc);
    z[HD + t] = fmaxf(acc, 0.f);
    __syncthreads();
    float invc = 1.f / fmaxf((float)(sb[1] - sb[0]), 1.f);
    z[t] = pooled[b * HD + t] * invc;
    __syncthreads();
    float a1 = f1b[t];
    for (int k = 0; k < 2 * HD; k++) a1 = fmaf(z[k], f1W[k * HD + t], a1);
    z1s[t] = fmaxf(a1, 0.f);
    __syncthreads();
    if (t < 2) {
        float o = f2b[t];
        for (int k = 0; k < HD; k++) o = fmaf(z1s[k], f2W[k * 2 + t], o);
        out[b * 2 + t] = o;
    }
}

extern "C" void kernel_launch(void* const* d_in, const int* in_sizes, int n_in,
                              void* d_out, int out_size, void* d_ws, size_t ws_size,
                              hipStream_t stream) {
    const float* x         = (const float*)d_in[0];
    const int*   ei        = (const int*)d_in[1];
    const float* edge_attr = (const float*)d_in[2];
    const float* u         = (const float*)d_in[3];
    const int*   batch     = (const int*)d_in[4];
    const float* node_W    = (const float*)d_in[5];
    const float* node_b    = (const float*)d_in[6];
    const float* eemb_W    = (const float*)d_in[7];
    const float* eemb_b    = (const float*)d_in[8];
    const float* lin_W     = (const float*)d_in[9];
    const float* att_src   = (const float*)d_in[10];
    const float* att_dst   = (const float*)d_in[11];
    const float* lin_eW    = (const float*)d_in[12];
    const float* att_e     = (const float*)d_in[13];
    const float* conv_b    = (const float*)d_in[14];
    const float* gW        = (const float*)d_in[15];
    const float* gb        = (const float*)d_in[16];
    const float* f1W       = (const float*)d_in[17];
    const float* f1b       = (const float*)d_in[18];
    const float* f2W       = (const float*)d_in[19];
    const float* f2b       = (const float*)d_in[20];

    const int N = in_sizes[0] / 3;
    const int E = in_sizes[2] / 4;
    const int B = in_sizes[3] / 10;
    const int* src = ei;
    const int* dst = ei + E;
    const int NB = (N + 255) / 256;   // scan blocks
    const size_t P4 = (size_t)(E + N) * 4;  // aed plane stride (floats)

    // workspace carve (fp32, then bf16, then ints; all region sizes keep 16B alignment)
    float* wsf = (float*)d_ws;
    float* h       = wsf;              wsf += (size_t)N * HD;
    float* a_s     = wsf;              wsf += (size_t)N * 4;
    float* a_d     = wsf;              wsf += (size_t)N * 4;
    float* aed     = wsf;              wsf += 3 * P4;
    float* pooled  = wsf;              wsf += (size_t)B * HD;
    u16* xp = (u16*)wsf;               wsf += (size_t)N * 128;   // N*256 bf16
    int* wsi = (int*)wsf;
    int2* csr_se = (int2*)wsi;         wsi += 2 * (size_t)E;     // 8B-aligned
    int* deg     = wsi;                wsi += N;
    int* row_ptr = wsi;                wsi += N + 1;
    int* cursor  = wsi;                wsi += N;
    int* tmp     = wsi;                wsi += N;
    int* bsum    = wsi;                wsi += NB + 1;

    k_init<<<(N * HD + 255) / 256, 256, 0, stream>>>(x, node_W, node_b, h,
                                                     deg, cursor, pooled, N, B);
    k_deg<<<(E + 255) / 256, 256, 0, stream>>>(dst, deg, E, N);
    k_scan1<<<NB, 256, 0, stream>>>(deg, tmp, bsum, N);
    k_scan23<<<NB, 256, 0, stream>>>(tmp, bsum, row_ptr, N);
    k_csr<<<(E + 255) / 256, 256, 0, stream>>>(src, dst, row_ptr, cursor,
                                               csr_se, E, N);
    k_ee<<<(E + 1023) / 1024, 256, 0, stream>>>(edge_attr, eemb_W, eemb_b, lin_eW, att_e,
                                                csr_se, aed, E, N);
    k_selfed<<<NB, 256, 0, stream>>>(row_ptr, aed, E, N);
    for (int i = 0; i < 3; i++) {
        k_xp<<<(N + NPB - 1) / NPB, 256, 0, stream>>>(h, lin_W + (size_t)i * HD * 256,
                                                      att_src + (size_t)i * 256,
                                                      att_dst + (size_t)i * 256,
                                                      xp, a_s, a_d, N);
        k_gat<<<(N + 3) / 4, 256, 0, stream>>>(xp, a_s, a_d, aed + (size_t)i * P4,
                                               row_ptr, csr_se,
                                               conv_b + (size_t)i * HD, h,
                                               batch, (i == 2) ? pooled : nullptr,
                                               N, E);
    }
    k_mlp<<<B, 64, 0, stream>>>(u, gW, gb, pooled, batch, f1W, f1b, f2W, f2b,
                                (float*)d_out, N, B);
}

// Round 6
// 402.977 us; speedup vs baseline: 1.3147x; 1.3147x over previous
//
#include <hip/hip_runtime.h>
#include <hip/hip_bf16.h>

#define HD 64

typedef unsigned short u16;

__device__ __forceinline__ float lrelu(float x) { return x > 0.f ? x : 0.2f * x; }
__device__ __forceinline__ int clampi(int v, int maxv) {
    return v < 0 ? 0 : (v >= maxv ? maxv - 1 : v);
}
__device__ __forceinline__ float bf2f(u16 u) {
    return __uint_as_float(((unsigned int)u) << 16);
}
// round-to-nearest-even fp32 -> bf16 (bit-level; inputs are finite)
__device__ __forceinline__ u16 f2bf(float f) {
    unsigned int u = __float_as_uint(f);
    unsigned int lsb = (u >> 16) & 1u;
    u += 0x7fffu + lsb;
    return (u16)(u >> 16);
}

// ---------------- init (zero deg/cursor/pooled) + node embedding fused ----------------
__global__ void k_init(const float* __restrict__ x, const float* __restrict__ W,
                       const float* __restrict__ b, float* __restrict__ h,
                       int* deg, int* cursor, float* pooled, int N, int B) {
    int i = blockIdx.x * blockDim.x + threadIdx.x;
    if (i < N) { deg[i] = 0; cursor[i] = 0; }
    if (i < B * HD) pooled[i] = 0.f;
    if (i < N * HD) {
        int n = i >> 6, c = i & 63;
        float acc = b[c];
        acc = fmaf(x[n * 3 + 0], W[0 * HD + c], acc);
        acc = fmaf(x[n * 3 + 1], W[1 * HD + c], acc);
        acc = fmaf(x[n * 3 + 2], W[2 * HD + c], acc);
        h[i] = fmaxf(acc, 0.f);
    }
}

// ---------------- degree histogram over dst ----------------
__global__ void k_deg(const int* __restrict__ dst, int* __restrict__ deg, int E, int N) {
    int e = blockIdx.x * blockDim.x + threadIdx.x;
    if (e < E) atomicAdd(&deg[clampi(dst[e], N)], 1);
}

// ---------------- hierarchical scan (2 kernels) ----------------
__global__ void k_scan1(const int* __restrict__ deg, int* __restrict__ tmp,
                        int* __restrict__ bsum, int N) {
    __shared__ int s[256];
    int tid = threadIdx.x;
    int i = blockIdx.x * 256 + tid;
    int v = (i < N) ? deg[i] : 0;
    s[tid] = v;
    __syncthreads();
    for (int off = 1; off < 256; off <<= 1) {
        int t = (tid >= off) ? s[tid - off] : 0;
        __syncthreads();
        s[tid] += t;
        __syncthreads();
    }
    if (i < N) tmp[i] = s[tid];
    if (tid == 255) bsum[blockIdx.x] = s[255];
}
// each block: wave 0 redundantly computes exclusive prefix of bsum[0..bid), then writes row_ptr
__global__ void k_scan23(const int* __restrict__ tmp, const int* __restrict__ bsum,
                         int* __restrict__ row_ptr, int N) {
    __shared__ int s_off;
    int t = threadIdx.x;
    if (t < 64) {
        int cnt = blockIdx.x;  // number of preceding blocks
        int v = 0;
        for (int base = 0; base < cnt; base += 64)
            if (base + t < cnt) v += bsum[base + t];
        #pragma unroll
        for (int o = 32; o > 0; o >>= 1) v += __shfl_xor(v, o);
        if (t == 0) s_off = v;
    }
    __syncthreads();
    int i = blockIdx.x * 256 + t;
    if (i == 0) row_ptr[0] = 0;
    if (i < N) row_ptr[i + 1] = tmp[i] + s_off;
}

// ---------------- CSR scatter; packed {src, eid} int2 per slot ----------------
__global__ void k_csr(const int* __restrict__ src, const int* __restrict__ dst,
                      const int* __restrict__ row_ptr, int* __restrict__ cursor,
                      int2* __restrict__ csr_se, int E, int N) {
    int e = blockIdx.x * blockDim.x + threadIdx.x;
    if (e >= E) return;
    int d = clampi(dst[e], N);
    int pos = row_ptr[d] + atomicAdd(&cursor[d], 1);
    if (pos < E) csr_se[pos] = make_int2(clampi(src[e], N), e);
}

// ---------------- ONCE: a_ed for all 3 layers x 4 heads, CSR order ----------------
// planar output: aed[l][(E+N)][4]
__global__ __launch_bounds__(256) void k_ee(
    const float* __restrict__ edge_attr, const float* __restrict__ eW,
    const float* __restrict__ eB, const float* __restrict__ lin_eW,
    const float* __restrict__ att_e, const int2* __restrict__ csr_se,
    float* __restrict__ aed, int E, int N) {
    __shared__ float s_ew[256];    // [k*64+d]
    __shared__ float s_eb[64];
    __shared__ float s_wred[768];  // [l*256 + h*64 + d]
    size_t P4 = (size_t)(E + N) * 4;
    int t = threadIdx.x;
    s_ew[t] = eW[t];
    if (t < 64) s_eb[t] = eB[t];
    for (int idx = t; idx < 768; idx += 256) {
        int l = idx >> 8, hd = idx & 255, hh = hd >> 6, d = hd & 63;
        const float* We = lin_eW + (size_t)l * HD * 256;
        const float* ae = att_e + (size_t)l * 256;
        float acc = 0.f;
        for (int c = 0; c < 64; c++)
            acc = fmaf(We[d * 256 + hh * 64 + c], ae[hh * 64 + c], acc);
        s_wred[idx] = acc;
    }
    __syncthreads();
    int j0 = (blockIdx.x * 256 + t) * 4;
    if (j0 >= E) return;
    float4 a[4];
    int nv = 0;
    #pragma unroll
    for (int q = 0; q < 4; q++) {
        int j = j0 + q;
        if (j < E) {
            a[q] = *(const float4*)(edge_attr + (size_t)csr_se[j].y * 4);
            nv = q + 1;
        } else {
            a[q] = make_float4(0.f, 0.f, 0.f, 0.f);
        }
    }
    float acc[4][12];
    #pragma unroll
    for (int q = 0; q < 4; q++)
        #pragma unroll
        for (int m = 0; m < 12; m++) acc[q][m] = 0.f;
    for (int k = 0; k < HD; k++) {
        float e0 = s_ew[k], e1 = s_ew[64 + k], e2 = s_ew[128 + k], e3 = s_ew[192 + k];
        float eb = s_eb[k];
        float w[12];
        #pragma unroll
        for (int m = 0; m < 12; m++)
            w[m] = s_wred[(m >> 2) * 256 + (m & 3) * 64 + k];
        #pragma unroll
        for (int q = 0; q < 4; q++) {
            float v = fmaf(a[q].x, e0, fmaf(a[q].y, e1,
                      fmaf(a[q].z, e2, fmaf(a[q].w, e3, eb))));
            v = fmaxf(v, 0.f);
            #pragma unroll
            for (int m = 0; m < 12; m++) acc[q][m] = fmaf(v, w[m], acc[q][m]);
        }
    }
    #pragma unroll
    for (int q = 0; q < 4; q++) {
        if (q >= nv) break;
        #pragma unroll
        for (int l = 0; l < 3; l++) {
            *(float4*)(aed + l * P4 + (size_t)(j0 + q) * 4) =
                make_float4(acc[q][l * 4 + 0], acc[q][l * 4 + 1],
                            acc[q][l * 4 + 2], acc[q][l * 4 + 3]);
        }
    }
}

// ---------------- ONCE: self-loop a_ed rows by LINEARITY ----------------
__global__ void k_selfed(const int* __restrict__ row_ptr, float* __restrict__ aed,
                         int E, int N) {
    int n = blockIdx.x * blockDim.x + threadIdx.x;
    if (n >= N) return;
    size_t P4 = (size_t)(E + N) * 4;
    int r0 = row_ptr[n], r1 = row_ptr[n + 1];
    float acc[12];
    #pragma unroll
    for (int m = 0; m < 12; m++) acc[m] = 0.f;
    for (int j = r0; j < r1; j++) {
        #pragma unroll
        for (int l = 0; l < 3; l++) {
            float4 v = *(const float4*)(aed + l * P4 + (size_t)j * 4);
            acc[l * 4 + 0] += v.x; acc[l * 4 + 1] += v.y;
            acc[l * 4 + 2] += v.z; acc[l * 4 + 3] += v.w;
        }
    }
    float inv = 1.f / fmaxf((float)(r1 - r0), 1.f);
    #pragma unroll
    for (int l = 0; l < 3; l++) {
        *(float4*)(aed + l * P4 + (size_t)(E + n) * 4) =
            make_float4(acc[l * 4 + 0] * inv, acc[l * 4 + 1] * inv,
                        acc[l * 4 + 2] * inv, acc[l * 4 + 3] * inv);
    }
}

// ---------------- per-layer: xp = h@W, 8 nodes/block, broadcast h loads, NO LDS ----------
// All lanes of a wave read the same h line (L1 broadcast). NPB=8 keeps live VGPRs ~60
// (8 acc + 8x4 h + 4 W) -- the NPB=32 version spilled everything (VGPR_Count=28, 60us).
#define NPB 8
__global__ __launch_bounds__(256) void k_xp(
    const float* __restrict__ h, const float* __restrict__ W,
    const float* __restrict__ asrc, const float* __restrict__ adst,
    u16* __restrict__ xp, float* __restrict__ a_s, float* __restrict__ a_d, int N) {
    int n0 = blockIdx.x * NPB;
    int c = threadIdx.x;
    int nlim = N - n0;  // >= 1
    const float* hp = h + (size_t)n0 * HD;
    float acc[NPB];
    #pragma unroll
    for (int k = 0; k < NPB; k++) acc[k] = 0.f;
    for (int d = 0; d < HD; d += 4) {
        float w0 = W[(d + 0) * 256 + c];
        float w1 = W[(d + 1) * 256 + c];
        float w2 = W[(d + 2) * 256 + c];
        float w3 = W[(d + 3) * 256 + c];
        #pragma unroll
        for (int k = 0; k < NPB; k++) {
            int kk = (k < nlim) ? k : 0;  // clamp for tail block
            float4 hv = *(const float4*)(hp + kk * HD + d);
            acc[k] = fmaf(hv.x, w0, acc[k]);
            acc[k] = fmaf(hv.y, w1, acc[k]);
            acc[k] = fmaf(hv.z, w2, acc[k]);
            acc[k] = fmaf(hv.w, w3, acc[k]);
        }
    }
    float as_ = asrc[c], ad_ = adst[c];
    int hh = c >> 6, cc = c & 63;
    #pragma unroll
    for (int k = 0; k < NPB; k++) {
        int nn = n0 + k;
        if (nn >= N) break;  // wave-uniform
        float ps = acc[k] * as_;
        float pd = acc[k] * ad_;
        #pragma unroll
        for (int o = 32; o > 0; o >>= 1) {
            ps += __shfl_xor(ps, o);
            pd += __shfl_xor(pd, o);
        }
        xp[(size_t)nn * 256 + c] = f2bf(acc[k]);
        if (cc == 0) { a_s[nn * 4 + hh] = ps; a_d[nn * 4 + hh] = pd; }
    }
}

// ---------------- per-layer GAT aggregate with fused attention weights ----------------
// (round-4 version, untouched: adding a pooling epilogue here caused a spill
//  catastrophe -- VGPR_Count dropped to 32 and dur went 47 -> 163us)
__global__ __launch_bounds__(256) void k_gat(
    const u16* __restrict__ xp, const float* __restrict__ a_s,
    const float* __restrict__ a_d, const float* __restrict__ aedl,
    const int* __restrict__ row_ptr, const int2* __restrict__ csr_se,
    const float* __restrict__ convb, float* __restrict__ h_out, int N, int E) {
    int wave = threadIdx.x >> 6, lane = threadIdx.x & 63;
    int n = blockIdx.x * 4 + wave;
    if (n >= N) return;
    int g = lane >> 4, p = lane & 15;
    int r0 = row_ptr[n], r1 = row_ptr[n + 1];
    float4 ad4 = *(const float4*)(a_d + (size_t)n * 4);
    float a00 = 0.f, a01 = 0.f, a02 = 0.f, a03 = 0.f;
    float a10 = 0.f, a11 = 0.f, a12 = 0.f, a13 = 0.f;
    float a20 = 0.f, a21 = 0.f, a22 = 0.f, a23 = 0.f;
    float a30 = 0.f, a31 = 0.f, a32 = 0.f, a33 = 0.f;
    float d0 = 0.f, d1 = 0.f, d2 = 0.f, d3 = 0.f;
    if (g == 0) {
        // self loop: src = n
        float4 as4 = *(const float4*)(a_s + (size_t)n * 4);
        float4 p4 = *(const float4*)(aedl + (size_t)(E + n) * 4);
        float w0 = __expf(lrelu(as4.x + ad4.x + p4.x));
        float w1 = __expf(lrelu(as4.y + ad4.y + p4.y));
        float w2 = __expf(lrelu(as4.z + ad4.z + p4.z));
        float w3 = __expf(lrelu(as4.w + ad4.w + p4.w));
        const u16* row = xp + (size_t)n * 256 + p * 4;
        ushort4 v0 = *(const ushort4*)(row);
        ushort4 v1 = *(const ushort4*)(row + 64);
        ushort4 v2 = *(const ushort4*)(row + 128);
        ushort4 v3 = *(const ushort4*)(row + 192);
        d0 += w0; d1 += w1; d2 += w2; d3 += w3;
        a00 = fmaf(w0, bf2f(v0.x), a00); a01 = fmaf(w0, bf2f(v0.y), a01);
        a02 = fmaf(w0, bf2f(v0.z), a02); a03 = fmaf(w0, bf2f(v0.w), a03);
        a10 = fmaf(w1, bf2f(v1.x), a10); a11 = fmaf(w1, bf2f(v1.y), a11);
        a12 = fmaf(w1, bf2f(v1.z), a12); a13 = fmaf(w1, bf2f(v1.w), a13);
        a20 = fmaf(w2, bf2f(v2.x), a20); a21 = fmaf(w2, bf2f(v2.y), a21);
        a22 = fmaf(w2, bf2f(v2.z), a22); a23 = fmaf(w2, bf2f(v2.w), a23);
        a30 = fmaf(w3, bf2f(v3.x), a30); a31 = fmaf(w3, bf2f(v3.y), a31);
        a32 = fmaf(w3, bf2f(v3.z), a32); a33 = fmaf(w3, bf2f(v3.w), a33);
    }
    int j = r0 + g;
    int2 se = (j < r1) ? csr_se[j] : make_int2(0, 0);
    for (; j < r1; j += 4) {
        int jn = j + 4;
        int2 se_n = (jn < r1) ? csr_se[jn] : make_int2(0, 0);  // prefetch
        int s = se.x;
        float4 as4 = *(const float4*)(a_s + (size_t)s * 4);
        float4 p4 = *(const float4*)(aedl + (size_t)j * 4);
        float w0 = __expf(lrelu(as4.x + ad4.x + p4.x));
        float w1 = __expf(lrelu(as4.y + ad4.y + p4.y));
        float w2 = __expf(lrelu(as4.z + ad4.z + p4.z));
        float w3 = __expf(lrelu(as4.w + ad4.w + p4.w));
        const u16* row = xp + (size_t)s * 256 + p * 4;
        ushort4 v0 = *(const ushort4*)(row);
        ushort4 v1 = *(const ushort4*)(row + 64);
        ushort4 v2 = *(const ushort4*)(row + 128);
        ushort4 v3 = *(const ushort4*)(row + 192);
        d0 += w0; d1 += w1; d2 += w2; d3 += w3;
        a00 = fmaf(w0, bf2f(v0.x), a00); a01 = fmaf(w0, bf2f(v0.y), a01);
        a02 = fmaf(w0, bf2f(v0.z), a02); a03 = fmaf(w0, bf2f(v0.w), a03);
        a10 = fmaf(w1, bf2f(v1.x), a10); a11 = fmaf(w1, bf2f(v1.y), a11);
        a12 = fmaf(w1, bf2f(v1.z), a12); a13 = fmaf(w1, bf2f(v1.w), a13);
        a20 = fmaf(w2, bf2f(v2.x), a20); a21 = fmaf(w2, bf2f(v2.y), a21);
        a22 = fmaf(w2, bf2f(v2.z), a22); a23 = fmaf(w2, bf2f(v2.w), a23);
        a30 = fmaf(w3, bf2f(v3.x), a30); a31 = fmaf(w3, bf2f(v3.y), a31);
        a32 = fmaf(w3, bf2f(v3.z), a32); a33 = fmaf(w3, bf2f(v3.w), a33);
        se = se_n;
    }
    d0 += __shfl_xor(d0, 16); d0 += __shfl_xor(d0, 32);
    d1 += __shfl_xor(d1, 16); d1 += __shfl_xor(d1, 32);
    d2 += __shfl_xor(d2, 16); d2 += __shfl_xor(d2, 32);
    d3 += __shfl_xor(d3, 16); d3 += __shfl_xor(d3, 32);
    float i0 = 1.f / d0, i1 = 1.f / d1, i2 = 1.f / d2, i3 = 1.f / d3;
    float m0 = a00 * i0 + a10 * i1 + a20 * i2 + a30 * i3;
    float m1 = a01 * i0 + a11 * i1 + a21 * i2 + a31 * i3;
    float m2 = a02 * i0 + a12 * i1 + a22 * i2 + a32 * i3;
    float m3 = a03 * i0 + a13 * i1 + a23 * i2 + a33 * i3;
    m0 += __shfl_xor(m0, 16); m0 += __shfl_xor(m0, 32);
    m1 += __shfl_xor(m1, 16); m1 += __shfl_xor(m1, 32);
    m2 += __shfl_xor(m2, 16); m2 += __shfl_xor(m2, 32);
    m3 += __shfl_xor(m3, 16); m3 += __shfl_xor(m3, 32);
    if (lane < 16) {
        int c = p * 4;
        h_out[(size_t)n * HD + c + 0] = fmaxf(0.25f * m0 + convb[c + 0], 0.f);
        h_out[(size_t)n * HD + c + 1] = fmaxf(0.25f * m1 + convb[c + 1], 0.f);
        h_out[(size_t)n * HD + c + 2] = fmaxf(0.25f * m2 + convb[c + 2], 0.f);
        h_out[(size_t)n * HD + c + 3] = fmaxf(0.25f * m3 + convb[c + 3], 0.f);
    }
}

// ---------------- global pool, node-parallel with atomics (round-0 style, cheap) --------
__global__ void k_pool(const float* __restrict__ h, const int* __restrict__ batch,
                       float* __restrict__ pooled, int N, int B) {
    int i = blockIdx.x * blockDim.x + threadIdx.x;
    if (i >= N * HD) return;
    int n = i >> 6, c = i & 63;
    int b = clampi(batch[n], B);
    atomicAdd(&pooled[b * HD + c], h[i]);
}

// ---------------- final MLP: B blocks x 64 threads; len via binary search ----------------
__global__ void k_mlp(const float* __restrict__ u, const float* __restrict__ gW,
                      const float* __restrict__ gb, const float* __restrict__ pooled,
                      const int* __restrict__ batch, const float* __restrict__ f1W,
                      const float* __restrict__ f1b, const float* __restrict__ f2W,
                      const float* __restrict__ f2b, float* __restrict__ out,
                      int N, int B) {
    __shared__ float z[2 * HD];
    __shared__ float z1s[HD];
    __shared__ int sb[2];
    int b = blockIdx.x, t = threadIdx.x;  // 64 threads
    if (t < 2) {
        int target = b + t;
        int lo = 0, hi = N;
        while (lo < hi) {
            int m = (lo + hi) >> 1;
            if (batch[m] < target) lo = m + 1; else hi = m;
        }
        sb[t] = lo;
    }
    float acc = gb[t];
    for (int k = 0; k < 10; k++) acc = fmaf(u[b * 10 + k], gW[k * HD + t], acc);
    z[HD + t] = fmaxf(acc, 0.f);
    __syncthreads();
    float invc = 1.f / fmaxf((float)(sb[1] - sb[0]), 1.f);
    z[t] = pooled[b * HD + t] * invc;
    __syncthreads();
    float a1 = f1b[t];
    for (int k = 0; k < 2 * HD; k++) a1 = fmaf(z[k], f1W[k * HD + t], a1);
    z1s[t] = fmaxf(a1, 0.f);
    __syncthreads();
    if (t < 2) {
        float o = f2b[t];
        for (int k = 0; k < HD; k++) o = fmaf(z1s[k], f2W[k * 2 + t], o);
        out[b * 2 + t] = o;
    }
}

extern "C" void kernel_launch(void* const* d_in, const int* in_sizes, int n_in,
                              void* d_out, int out_size, void* d_ws, size_t ws_size,
                              hipStream_t stream) {
    const float* x         = (const float*)d_in[0];
    const int*   ei        = (const int*)d_in[1];
    const float* edge_attr = (const float*)d_in[2];
    const float* u         = (const float*)d_in[3];
    const int*   batch     = (const int*)d_in[4];
    const float* node_W    = (const float*)d_in[5];
    const float* node_b    = (const float*)d_in[6];
    const float* eemb_W    = (const float*)d_in[7];
    const float* eemb_b    = (const float*)d_in[8];
    const float* lin_W     = (const float*)d_in[9];
    const float* att_src   = (const float*)d_in[10];
    const float* att_dst   = (const float*)d_in[11];
    const float* lin_eW    = (const float*)d_in[12];
    const float* att_e     = (const float*)d_in[13];
    const float* conv_b    = (const float*)d_in[14];
    const float* gW        = (const float*)d_in[15];
    const float* gb        = (const float*)d_in[16];
    const float* f1W       = (const float*)d_in[17];
    const float* f1b       = (const float*)d_in[18];
    const float* f2W       = (const float*)d_in[19];
    const float* f2b       = (const float*)d_in[20];

    const int N = in_sizes[0] / 3;
    const int E = in_sizes[2] / 4;
    const int B = in_sizes[3] / 10;
    const int* src = ei;
    const int* dst = ei + E;
    const int NB = (N + 255) / 256;   // scan blocks
    const size_t P4 = (size_t)(E + N) * 4;  // aed plane stride (floats)

    // workspace carve (fp32, then bf16, then ints; all region sizes keep 16B alignment)
    float* wsf = (float*)d_ws;
    float* h       = wsf;              wsf += (size_t)N * HD;
    float* a_s     = wsf;              wsf += (size_t)N * 4;
    float* a_d     = wsf;              wsf += (size_t)N * 4;
    float* aed     = wsf;              wsf += 3 * P4;
    float* pooled  = wsf;              wsf += (size_t)B * HD;
    u16* xp = (u16*)wsf;               wsf += (size_t)N * 128;   // N*256 bf16
    int* wsi = (int*)wsf;
    int2* csr_se = (int2*)wsi;         wsi += 2 * (size_t)E;     // 8B-aligned
    int* deg     = wsi;                wsi += N;
    int* row_ptr = wsi;                wsi += N + 1;
    int* cursor  = wsi;                wsi += N;
    int* tmp     = wsi;                wsi += N;
    int* bsum    = wsi;                wsi += NB + 1;

    k_init<<<(N * HD + 255) / 256, 256, 0, stream>>>(x, node_W, node_b, h,
                                                     deg, cursor, pooled, N, B);
    k_deg<<<(E + 255) / 256, 256, 0, stream>>>(dst, deg, E, N);
    k_scan1<<<NB, 256, 0, stream>>>(deg, tmp, bsum, N);
    k_scan23<<<NB, 256, 0, stream>>>(tmp, bsum, row_ptr, N);
    k_csr<<<(E + 255) / 256, 256, 0, stream>>>(src, dst, row_ptr, cursor,
                                               csr_se, E, N);
    k_ee<<<(E + 1023) / 1024, 256, 0, stream>>>(edge_attr, eemb_W, eemb_b, lin_eW, att_e,
                                                csr_se, aed, E, N);
    k_selfed<<<NB, 256, 0, stream>>>(row_ptr, aed, E, N);
    for (int i = 0; i < 3; i++) {
        k_xp<<<(N + NPB - 1) / NPB, 256, 0, stream>>>(h, lin_W + (size_t)i * HD * 256,
                                                      att_src + (size_t)i * 256,
                                                      att_dst + (size_t)i * 256,
                                                      xp, a_s, a_d, N);
        k_gat<<<(N + 3) / 4, 256, 0, stream>>>(xp, a_s, a_d, aed + (size_t)i * P4,
                                               row_ptr, csr_se,
                                               conv_b + (size_t)i * HD, h, N, E);
    }
    k_pool<<<(N * HD + 255) / 256, 256, 0, stream>>>(h, batch, pooled, N, B);
    k_mlp<<<B, 64, 0, stream>>>(u, gW, gb, pooled, batch, f1W, f1b, f2W, f2b,
                                (float*)d_out, N, B);
}

// Round 7
// 376.326 us; speedup vs baseline: 1.4078x; 1.0708x over previous
//
#include <hip/hip_runtime.h>
#include <hip/hip_bf16.h>

#define HD 64

typedef unsigned short u16;

__device__ __forceinline__ float lrelu(float x) { return x > 0.f ? x : 0.2f * x; }
__device__ __forceinline__ int clampi(int v, int maxv) {
    return v < 0 ? 0 : (v >= maxv ? maxv - 1 : v);
}
__device__ __forceinline__ float bf2f(u16 u) {
    return __uint_as_float(((unsigned int)u) << 16);
}
// round-to-nearest-even fp32 -> bf16 (bit-level; inputs are finite)
__device__ __forceinline__ u16 f2bf(float f) {
    unsigned int u = __float_as_uint(f);
    unsigned int lsb = (u >> 16) & 1u;
    u += 0x7fffu + lsb;
    return (u16)(u >> 16);
}

// ---------------- init (zero deg/cursor/pooled) + node embedding fused ----------------
__global__ void k_init(const float* __restrict__ x, const float* __restrict__ W,
                       const float* __restrict__ b, float* __restrict__ h,
                       int* deg, int* cursor, float* pooled, int N, int B) {
    int i = blockIdx.x * blockDim.x + threadIdx.x;
    if (i < N) { deg[i] = 0; cursor[i] = 0; }
    if (i < B * HD) pooled[i] = 0.f;
    if (i < N * HD) {
        int n = i >> 6, c = i & 63;
        float acc = b[c];
        acc = fmaf(x[n * 3 + 0], W[0 * HD + c], acc);
        acc = fmaf(x[n * 3 + 1], W[1 * HD + c], acc);
        acc = fmaf(x[n * 3 + 2], W[2 * HD + c], acc);
        h[i] = fmaxf(acc, 0.f);
    }
}

// ---------------- degree histogram over dst ----------------
__global__ void k_deg(const int* __restrict__ dst, int* __restrict__ deg, int E, int N) {
    int e = blockIdx.x * blockDim.x + threadIdx.x;
    if (e < E) atomicAdd(&deg[clampi(dst[e], N)], 1);
}

// ---------------- hierarchical scan (2 kernels) ----------------
__global__ void k_scan1(const int* __restrict__ deg, int* __restrict__ tmp,
                        int* __restrict__ bsum, int N) {
    __shared__ int s[256];
    int tid = threadIdx.x;
    int i = blockIdx.x * 256 + tid;
    int v = (i < N) ? deg[i] : 0;
    s[tid] = v;
    __syncthreads();
    for (int off = 1; off < 256; off <<= 1) {
        int t = (tid >= off) ? s[tid - off] : 0;
        __syncthreads();
        s[tid] += t;
        __syncthreads();
    }
    if (i < N) tmp[i] = s[tid];
    if (tid == 255) bsum[blockIdx.x] = s[255];
}
// each block: wave 0 redundantly computes exclusive prefix of bsum[0..bid), then writes row_ptr
__global__ void k_scan23(const int* __restrict__ tmp, const int* __restrict__ bsum,
                         int* __restrict__ row_ptr, int N) {
    __shared__ int s_off;
    int t = threadIdx.x;
    if (t < 64) {
        int cnt = blockIdx.x;  // number of preceding blocks
        int v = 0;
        for (int base = 0; base < cnt; base += 64)
            if (base + t < cnt) v += bsum[base + t];
        #pragma unroll
        for (int o = 32; o > 0; o >>= 1) v += __shfl_xor(v, o);
        if (t == 0) s_off = v;
    }
    __syncthreads();
    int i = blockIdx.x * 256 + t;
    if (i == 0) row_ptr[0] = 0;
    if (i < N) row_ptr[i + 1] = tmp[i] + s_off;
}

// ---------------- CSR scatter; packed {src, eid} int2 per slot ----------------
__global__ void k_csr(const int* __restrict__ src, const int* __restrict__ dst,
                      const int* __restrict__ row_ptr, int* __restrict__ cursor,
                      int2* __restrict__ csr_se, int E, int N) {
    int e = blockIdx.x * blockDim.x + threadIdx.x;
    if (e >= E) return;
    int d = clampi(dst[e], N);
    int pos = row_ptr[d] + atomicAdd(&cursor[d], 1);
    if (pos < E) csr_se[pos] = make_int2(clampi(src[e], N), e);
}

// ---------------- ONCE: a_ed for all 3 layers x 4 heads, CSR order ----------------
// planar output: aed[l][(E+N)][4]
__global__ __launch_bounds__(256) void k_ee(
    const float* __restrict__ edge_attr, const float* __restrict__ eW,
    const float* __restrict__ eB, const float* __restrict__ lin_eW,
    const float* __restrict__ att_e, const int2* __restrict__ csr_se,
    float* __restrict__ aed, int E, int N) {
    __shared__ float s_ew[256];    // [k*64+d]
    __shared__ float s_eb[64];
    __shared__ float s_wred[768];  // [l*256 + h*64 + d]
    size_t P4 = (size_t)(E + N) * 4;
    int t = threadIdx.x;
    s_ew[t] = eW[t];
    if (t < 64) s_eb[t] = eB[t];
    for (int idx = t; idx < 768; idx += 256) {
        int l = idx >> 8, hd = idx & 255, hh = hd >> 6, d = hd & 63;
        const float* We = lin_eW + (size_t)l * HD * 256;
        const float* ae = att_e + (size_t)l * 256;
        float acc = 0.f;
        for (int c = 0; c < 64; c++)
            acc = fmaf(We[d * 256 + hh * 64 + c], ae[hh * 64 + c], acc);
        s_wred[idx] = acc;
    }
    __syncthreads();
    int j0 = (blockIdx.x * 256 + t) * 4;
    if (j0 >= E) return;
    float4 a[4];
    int nv = 0;
    #pragma unroll
    for (int q = 0; q < 4; q++) {
        int j = j0 + q;
        if (j < E) {
            a[q] = *(const float4*)(edge_attr + (size_t)csr_se[j].y * 4);
            nv = q + 1;
        } else {
            a[q] = make_float4(0.f, 0.f, 0.f, 0.f);
        }
    }
    float acc[4][12];
    #pragma unroll
    for (int q = 0; q < 4; q++)
        #pragma unroll
        for (int m = 0; m < 12; m++) acc[q][m] = 0.f;
    for (int k = 0; k < HD; k++) {
        float e0 = s_ew[k], e1 = s_ew[64 + k], e2 = s_ew[128 + k], e3 = s_ew[192 + k];
        float eb = s_eb[k];
        float w[12];
        #pragma unroll
        for (int m = 0; m < 12; m++)
            w[m] = s_wred[(m >> 2) * 256 + (m & 3) * 64 + k];
        #pragma unroll
        for (int q = 0; q < 4; q++) {
            float v = fmaf(a[q].x, e0, fmaf(a[q].y, e1,
                      fmaf(a[q].z, e2, fmaf(a[q].w, e3, eb))));
            v = fmaxf(v, 0.f);
            #pragma unroll
            for (int m = 0; m < 12; m++) acc[q][m] = fmaf(v, w[m], acc[q][m]);
        }
    }
    #pragma unroll
    for (int q = 0; q < 4; q++) {
        if (q >= nv) break;
        #pragma unroll
        for (int l = 0; l < 3; l++) {
            *(float4*)(aed + l * P4 + (size_t)(j0 + q) * 4) =
                make_float4(acc[q][l * 4 + 0], acc[q][l * 4 + 1],
                            acc[q][l * 4 + 2], acc[q][l * 4 + 3]);
        }
    }
}

// ---------------- ONCE: self-loop a_ed rows by LINEARITY ----------------
__global__ void k_selfed(const int* __restrict__ row_ptr, float* __restrict__ aed,
                         int E, int N) {
    int n = blockIdx.x * blockDim.x + threadIdx.x;
    if (n >= N) return;
    size_t P4 = (size_t)(E + N) * 4;
    int r0 = row_ptr[n], r1 = row_ptr[n + 1];
    float acc[12];
    #pragma unroll
    for (int m = 0; m < 12; m++) acc[m] = 0.f;
    for (int j = r0; j < r1; j++) {
        #pragma unroll
        for (int l = 0; l < 3; l++) {
            float4 v = *(const float4*)(aed + l * P4 + (size_t)j * 4);
            acc[l * 4 + 0] += v.x; acc[l * 4 + 1] += v.y;
            acc[l * 4 + 2] += v.z; acc[l * 4 + 3] += v.w;
        }
    }
    float inv = 1.f / fmaxf((float)(r1 - r0), 1.f);
    #pragma unroll
    for (int l = 0; l < 3; l++) {
        *(float4*)(aed + l * P4 + (size_t)(E + n) * 4) =
            make_float4(acc[l * 4 + 0] * inv, acc[l * 4 + 1] * inv,
                        acc[l * 4 + 2] * inv, acc[l * 4 + 3] * inv);
    }
}

// ---------------- per-layer: xp = h@W, 8 nodes/block, broadcast h loads, NO LDS ----------
// All lanes of a wave read the same h line (L1 broadcast). NPB=8 keeps live VGPRs ~60
// (8 acc + 8x4 h + 4 W) -- the NPB=32 version spilled everything (VGPR_Count=28, 60us).
#define NPB 8
__global__ __launch_bounds__(256) void k_xp(
    const float* __restrict__ h, const float* __restrict__ W,
    const float* __restrict__ asrc, const float* __restrict__ adst,
    u16* __restrict__ xp, float* __restrict__ a_s, float* __restrict__ a_d, int N) {
    int n0 = blockIdx.x * NPB;
    int c = threadIdx.x;
    int nlim = N - n0;  // >= 1
    const float* hp = h + (size_t)n0 * HD;
    float acc[NPB];
    #pragma unroll
    for (int k = 0; k < NPB; k++) acc[k] = 0.f;
    for (int d = 0; d < HD; d += 4) {
        float w0 = W[(d + 0) * 256 + c];
        float w1 = W[(d + 1) * 256 + c];
        float w2 = W[(d + 2) * 256 + c];
        float w3 = W[(d + 3) * 256 + c];
        #pragma unroll
        for (int k = 0; k < NPB; k++) {
            int kk = (k < nlim) ? k : 0;  // clamp for tail block
            float4 hv = *(const float4*)(hp + kk * HD + d);
            acc[k] = fmaf(hv.x, w0, acc[k]);
            acc[k] = fmaf(hv.y, w1, acc[k]);
            acc[k] = fmaf(hv.z, w2, acc[k]);
            acc[k] = fmaf(hv.w, w3, acc[k]);
        }
    }
    float as_ = asrc[c], ad_ = adst[c];
    int hh = c >> 6, cc = c & 63;
    #pragma unroll
    for (int k = 0; k < NPB; k++) {
        int nn = n0 + k;
        if (nn >= N) break;  // wave-uniform
        float ps = acc[k] * as_;
        float pd = acc[k] * ad_;
        #pragma unroll
        for (int o = 32; o > 0; o >>= 1) {
            ps += __shfl_xor(ps, o);
            pd += __shfl_xor(pd, o);
        }
        xp[(size_t)nn * 256 + c] = f2bf(acc[k]);
        if (cc == 0) { a_s[nn * 4 + hh] = ps; a_d[nn * 4 + hh] = pd; }
    }
}

// ---------------- per-layer GAT aggregate with fused attention weights ----------------
// (round-4 version, untouched: adding a pooling epilogue here caused a spill
//  catastrophe -- VGPR_Count dropped to 32 and dur went 47 -> 163us)
__global__ __launch_bounds__(256) void k_gat(
    const u16* __restrict__ xp, const float* __restrict__ a_s,
    const float* __restrict__ a_d, const float* __restrict__ aedl,
    const int* __restrict__ row_ptr, const int2* __restrict__ csr_se,
    const float* __restrict__ convb, float* __restrict__ h_out, int N, int E) {
    int wave = threadIdx.x >> 6, lane = threadIdx.x & 63;
    int n = blockIdx.x * 4 + wave;
    if (n >= N) return;
    int g = lane >> 4, p = lane & 15;
    int r0 = row_ptr[n], r1 = row_ptr[n + 1];
    float4 ad4 = *(const float4*)(a_d + (size_t)n * 4);
    float a00 = 0.f, a01 = 0.f, a02 = 0.f, a03 = 0.f;
    float a10 = 0.f, a11 = 0.f, a12 = 0.f, a13 = 0.f;
    float a20 = 0.f, a21 = 0.f, a22 = 0.f, a23 = 0.f;
    float a30 = 0.f, a31 = 0.f, a32 = 0.f, a33 = 0.f;
    float d0 = 0.f, d1 = 0.f, d2 = 0.f, d3 = 0.f;
    if (g == 0) {
        // self loop: src = n
        float4 as4 = *(const float4*)(a_s + (size_t)n * 4);
        float4 p4 = *(const float4*)(aedl + (size_t)(E + n) * 4);
        float w0 = __expf(lrelu(as4.x + ad4.x + p4.x));
        float w1 = __expf(lrelu(as4.y + ad4.y + p4.y));
        float w2 = __expf(lrelu(as4.z + ad4.z + p4.z));
        float w3 = __expf(lrelu(as4.w + ad4.w + p4.w));
        const u16* row = xp + (size_t)n * 256 + p * 4;
        ushort4 v0 = *(const ushort4*)(row);
        ushort4 v1 = *(const ushort4*)(row + 64);
        ushort4 v2 = *(const ushort4*)(row + 128);
        ushort4 v3 = *(const ushort4*)(row + 192);
        d0 += w0; d1 += w1; d2 += w2; d3 += w3;
        a00 = fmaf(w0, bf2f(v0.x), a00); a01 = fmaf(w0, bf2f(v0.y), a01);
        a02 = fmaf(w0, bf2f(v0.z), a02); a03 = fmaf(w0, bf2f(v0.w), a03);
        a10 = fmaf(w1, bf2f(v1.x), a10); a11 = fmaf(w1, bf2f(v1.y), a11);
        a12 = fmaf(w1, bf2f(v1.z), a12); a13 = fmaf(w1, bf2f(v1.w), a13);
        a20 = fmaf(w2, bf2f(v2.x), a20); a21 = fmaf(w2, bf2f(v2.y), a21);
        a22 = fmaf(w2, bf2f(v2.z), a22); a23 = fmaf(w2, bf2f(v2.w), a23);
        a30 = fmaf(w3, bf2f(v3.x), a30); a31 = fmaf(w3, bf2f(v3.y), a31);
        a32 = fmaf(w3, bf2f(v3.z), a32); a33 = fmaf(w3, bf2f(v3.w), a33);
    }
    int j = r0 + g;
    int2 se = (j < r1) ? csr_se[j] : make_int2(0, 0);
    for (; j < r1; j += 4) {
        int jn = j + 4;
        int2 se_n = (jn < r1) ? csr_se[jn] : make_int2(0, 0);  // prefetch
        int s = se.x;
        float4 as4 = *(const float4*)(a_s + (size_t)s * 4);
        float4 p4 = *(const float4*)(aedl + (size_t)j * 4);
        float w0 = __expf(lrelu(as4.x + ad4.x + p4.x));
        float w1 = __expf(lrelu(as4.y + ad4.y + p4.y));
        float w2 = __expf(lrelu(as4.z + ad4.z + p4.z));
        float w3 = __expf(lrelu(as4.w + ad4.w + p4.w));
        const u16* row = xp + (size_t)s * 256 + p * 4;
        ushort4 v0 = *(const ushort4*)(row);
        ushort4 v1 = *(const ushort4*)(row + 64);
        ushort4 v2 = *(const ushort4*)(row + 128);
        ushort4 v3 = *(const ushort4*)(row + 192);
        d0 += w0; d1 += w1; d2 += w2; d3 += w3;
        a00 = fmaf(w0, bf2f(v0.x), a00); a01 = fmaf(w0, bf2f(v0.y), a01);
        a02 = fmaf(w0, bf2f(v0.z), a02); a03 = fmaf(w0, bf2f(v0.w), a03);
        a10 = fmaf(w1, bf2f(v1.x), a10); a11 = fmaf(w1, bf2f(v1.y), a11);
        a12 = fmaf(w1, bf2f(v1.z), a12); a13 = fmaf(w1, bf2f(v1.w), a13);
        a20 = fmaf(w2, bf2f(v2.x), a20); a21 = fmaf(w2, bf2f(v2.y), a21);
        a22 = fmaf(w2, bf2f(v2.z), a22); a23 = fmaf(w2, bf2f(v2.w), a23);
        a30 = fmaf(w3, bf2f(v3.x), a30); a31 = fmaf(w3, bf2f(v3.y), a31);
        a32 = fmaf(w3, bf2f(v3.z), a32); a33 = fmaf(w3, bf2f(v3.w), a33);
        se = se_n;
    }
    d0 += __shfl_xor(d0, 16); d0 += __shfl_xor(d0, 32);
    d1 += __shfl_xor(d1, 16); d1 += __shfl_xor(d1, 32);
    d2 += __shfl_xor(d2, 16); d2 += __shfl_xor(d2, 32);
    d3 += __shfl_xor(d3, 16); d3 += __shfl_xor(d3, 32);
    float i0 = 1.f / d0, i1 = 1.f / d1, i2 = 1.f / d2, i3 = 1.f / d3;
    float m0 = a00 * i0 + a10 * i1 + a20 * i2 + a30 * i3;
    float m1 = a01 * i0 + a11 * i1 + a21 * i2 + a31 * i3;
    float m2 = a02 * i0 + a12 * i1 + a22 * i2 + a32 * i3;
    float m3 = a03 * i0 + a13 * i1 + a23 * i2 + a33 * i3;
    m0 += __shfl_xor(m0, 16); m0 += __shfl_xor(m0, 32);
    m1 += __shfl_xor(m1, 16); m1 += __shfl_xor(m1, 32);
    m2 += __shfl_xor(m2, 16); m2 += __shfl_xor(m2, 32);
    m3 += __shfl_xor(m3, 16); m3 += __shfl_xor(m3, 32);
    if (lane < 16) {
        int c = p * 4;
        h_out[(size_t)n * HD + c + 0] = fmaxf(0.25f * m0 + convb[c + 0], 0.f);
        h_out[(size_t)n * HD + c + 1] = fmaxf(0.25f * m1 + convb[c + 1], 0.f);
        h_out[(size_t)n * HD + c + 2] = fmaxf(0.25f * m2 + convb[c + 2], 0.f);
        h_out[(size_t)n * HD + c + 3] = fmaxf(0.25f * m3 + convb[c + 3], 0.f);
    }
}

// ---------------- global pool: batch is SORTED -> segmented reduce (round-1 proven) -------
// node-parallel atomic version measured ~45us (625-way contention/address); this one
// does ~16K atomics total.
#define PCHUNK 8
__global__ void k_pool(const float* __restrict__ h, const int* __restrict__ batch,
                       float* __restrict__ pooled, int N, int B) {
    int b = blockIdx.x / PCHUNK, q = blockIdx.x % PCHUNK;
    __shared__ int sb[2];
    __shared__ float sred[256];
    int t = threadIdx.x;
    if (t == 0 || t == 64) {
        int target = b + (t ? 1 : 0);
        int lo = 0, hi = N;
        while (lo < hi) {
            int m = (lo + hi) >> 1;
            if (batch[m] < target) lo = m + 1; else hi = m;
        }
        sb[t ? 1 : 0] = lo;
    }
    __syncthreads();
    int start = sb[0], end = sb[1];
    int len = end - start;
    int c0 = start + (int)(((long long)len * q) / PCHUNK);
    int c1 = start + (int)(((long long)len * (q + 1)) / PCHUNK);
    int c = t & 63, r = t >> 6;
    float acc = 0.f;
    for (int nidx = c0 + r; nidx < c1; nidx += 4)
        acc += h[(size_t)nidx * HD + c];
    sred[t] = acc;
    __syncthreads();
    if (t < 64) {
        float v = sred[t] + sred[64 + t] + sred[128 + t] + sred[192 + t];
        if (v != 0.f) atomicAdd(&pooled[b * HD + c], v);
    }
}

// ---------------- final MLP: B blocks x 64 threads; len via binary search ----------------
__global__ void k_mlp(const float* __restrict__ u, const float* __restrict__ gW,
                      const float* __restrict__ gb, const float* __restrict__ pooled,
                      const int* __restrict__ batch, const float* __restrict__ f1W,
                      const float* __restrict__ f1b, const float* __restrict__ f2W,
                      const float* __restrict__ f2b, float* __restrict__ out,
                      int N, int B) {
    __shared__ float z[2 * HD];
    __shared__ float z1s[HD];
    __shared__ int sb[2];
    int b = blockIdx.x, t = threadIdx.x;  // 64 threads
    if (t < 2) {
        int target = b + t;
        int lo = 0, hi = N;
        while (lo < hi) {
            int m = (lo + hi) >> 1;
            if (batch[m] < target) lo = m + 1; else hi = m;
        }
        sb[t] = lo;
    }
    float acc = gb[t];
    for (int k = 0; k < 10; k++) acc = fmaf(u[b * 10 + k], gW[k * HD + t], acc);
    z[HD + t] = fmaxf(acc, 0.f);
    __syncthreads();
    float invc = 1.f / fmaxf((float)(sb[1] - sb[0]), 1.f);
    z[t] = pooled[b * HD + t] * invc;
    __syncthreads();
    float a1 = f1b[t];
    for (int k = 0; k < 2 * HD; k++) a1 = fmaf(z[k], f1W[k * HD + t], a1);
    z1s[t] = fmaxf(a1, 0.f);
    __syncthreads();
    if (t < 2) {
        float o = f2b[t];
        for (int k = 0; k < HD; k++) o = fmaf(z1s[k], f2W[k * 2 + t], o);
        out[b * 2 + t] = o;
    }
}

extern "C" void kernel_launch(void* const* d_in, const int* in_sizes, int n_in,
                              void* d_out, int out_size, void* d_ws, size_t ws_size,
                              hipStream_t stream) {
    const float* x         = (const float*)d_in[0];
    const int*   ei        = (const int*)d_in[1];
    const float* edge_attr = (const float*)d_in[2];
    const float* u         = (const float*)d_in[3];
    const int*   batch     = (const int*)d_in[4];
    const float* node_W    = (const float*)d_in[5];
    const float* node_b    = (const float*)d_in[6];
    const float* eemb_W    = (const float*)d_in[7];
    const float* eemb_b    = (const float*)d_in[8];
    const float* lin_W     = (const float*)d_in[9];
    const float* att_src   = (const float*)d_in[10];
    const float* att_dst   = (const float*)d_in[11];
    const float* lin_eW    = (const float*)d_in[12];
    const float* att_e     = (const float*)d_in[13];
    const float* conv_b    = (const float*)d_in[14];
    const float* gW        = (const float*)d_in[15];
    const float* gb        = (const float*)d_in[16];
    const float* f1W       = (const float*)d_in[17];
    const float* f1b       = (const float*)d_in[18];
    const float* f2W       = (const float*)d_in[19];
    const float* f2b       = (const float*)d_in[20];

    const int N = in_sizes[0] / 3;
    const int E = in_sizes[2] / 4;
    const int B = in_sizes[3] / 10;
    const int* src = ei;
    const int* dst = ei + E;
    const int NB = (N + 255) / 256;   // scan blocks
    const size_t P4 = (size_t)(E + N) * 4;  // aed plane stride (floats)

    // workspace carve (fp32, then bf16, then ints; all region sizes keep 16B alignment)
    float* wsf = (float*)d_ws;
    float* h       = wsf;              wsf += (size_t)N * HD;
    float* a_s     = wsf;              wsf += (size_t)N * 4;
    float* a_d     = wsf;              wsf += (size_t)N * 4;
    float* aed     = wsf;              wsf += 3 * P4;
    float* pooled  = wsf;              wsf += (size_t)B * HD;
    u16* xp = (u16*)wsf;               wsf += (size_t)N * 128;   // N*256 bf16
    int* wsi = (int*)wsf;
    int2* csr_se = (int2*)wsi;         wsi += 2 * (size_t)E;     // 8B-aligned
    int* deg     = wsi;                wsi += N;
    int* row_ptr = wsi;                wsi += N + 1;
    int* cursor  = wsi;                wsi += N;
    int* tmp     = wsi;                wsi += N;
    int* bsum    = wsi;                wsi += NB + 1;

    k_init<<<(N * HD + 255) / 256, 256, 0, stream>>>(x, node_W, node_b, h,
                                                     deg, cursor, pooled, N, B);
    k_deg<<<(E + 255) / 256, 256, 0, stream>>>(dst, deg, E, N);
    k_scan1<<<NB, 256, 0, stream>>>(deg, tmp, bsum, N);
    k_scan23<<<NB, 256, 0, stream>>>(tmp, bsum, row_ptr, N);
    k_csr<<<(E + 255) / 256, 256, 0, stream>>>(src, dst, row_ptr, cursor,
                                               csr_se, E, N);
    k_ee<<<(E + 1023) / 1024, 256, 0, stream>>>(edge_attr, eemb_W, eemb_b, lin_eW, att_e,
                                                csr_se, aed, E, N);
    k_selfed<<<NB, 256, 0, stream>>>(row_ptr, aed, E, N);
    for (int i = 0; i < 3; i++) {
        k_xp<<<(N + NPB - 1) / NPB, 256, 0, stream>>>(h, lin_W + (size_t)i * HD * 256,
                                                      att_src + (size_t)i * 256,
                                                      att_dst + (size_t)i * 256,
                                                      xp, a_s, a_d, N);
        k_gat<<<(N + 3) / 4, 256, 0, stream>>>(xp, a_s, a_d, aed + (size_t)i * P4,
                                               row_ptr, csr_se,
                                               conv_b + (size_t)i * HD, h, N, E);
    }
    k_pool<<<B * PCHUNK, 256, 0, stream>>>(h, batch, pooled, N, B);
    k_mlp<<<B, 64, 0, stream>>>(u, gW, gb, pooled, batch, f1W, f1b, f2W, f2b,
                                (float*)d_out, N, B);
}

// Round 8
// 372.004 us; speedup vs baseline: 1.4241x; 1.0116x over previous
//
#include <hip/hip_runtime.h>
#include <hip/hip_bf16.h>

#define HD 64

typedef unsigned short u16;

__device__ __forceinline__ float lrelu(float x) { return x > 0.f ? x : 0.2f * x; }
__device__ __forceinline__ int clampi(int v, int maxv) {
    return v < 0 ? 0 : (v >= maxv ? maxv - 1 : v);
}
__device__ __forceinline__ float bf2f(u16 u) {
    return __uint_as_float(((unsigned int)u) << 16);
}
// extract bf16 pair packed in a u32 (little-endian): lo = bits[15:0], hi = bits[31:16]
__device__ __forceinline__ float bflo(unsigned int u) { return __uint_as_float(u << 16); }
__device__ __forceinline__ float bfhi(unsigned int u) { return __uint_as_float(u & 0xffff0000u); }
// round-to-nearest-even fp32 -> bf16 (bit-level; inputs are finite)
__device__ __forceinline__ u16 f2bf(float f) {
    unsigned int u = __float_as_uint(f);
    unsigned int lsb = (u >> 16) & 1u;
    u += 0x7fffu + lsb;
    return (u16)(u >> 16);
}

// ---------------- init (zero deg/cursor/pooled) + node embedding fused ----------------
__global__ void k_init(const float* __restrict__ x, const float* __restrict__ W,
                       const float* __restrict__ b, float* __restrict__ h,
                       int* deg, int* cursor, float* pooled, int N, int B) {
    int i = blockIdx.x * blockDim.x + threadIdx.x;
    if (i < N) { deg[i] = 0; cursor[i] = 0; }
    if (i < B * HD) pooled[i] = 0.f;
    if (i < N * HD) {
        int n = i >> 6, c = i & 63;
        float acc = b[c];
        acc = fmaf(x[n * 3 + 0], W[0 * HD + c], acc);
        acc = fmaf(x[n * 3 + 1], W[1 * HD + c], acc);
        acc = fmaf(x[n * 3 + 2], W[2 * HD + c], acc);
        h[i] = fmaxf(acc, 0.f);
    }
}

// ---------------- degree histogram over dst ----------------
__global__ void k_deg(const int* __restrict__ dst, int* __restrict__ deg, int E, int N) {
    int e = blockIdx.x * blockDim.x + threadIdx.x;
    if (e < E) atomicAdd(&deg[clampi(dst[e], N)], 1);
}

// ---------------- hierarchical scan (2 kernels) ----------------
__global__ void k_scan1(const int* __restrict__ deg, int* __restrict__ tmp,
                        int* __restrict__ bsum, int N) {
    __shared__ int s[256];
    int tid = threadIdx.x;
    int i = blockIdx.x * 256 + tid;
    int v = (i < N) ? deg[i] : 0;
    s[tid] = v;
    __syncthreads();
    for (int off = 1; off < 256; off <<= 1) {
        int t = (tid >= off) ? s[tid - off] : 0;
        __syncthreads();
        s[tid] += t;
        __syncthreads();
    }
    if (i < N) tmp[i] = s[tid];
    if (tid == 255) bsum[blockIdx.x] = s[255];
}
// each block: wave 0 redundantly computes exclusive prefix of bsum[0..bid), then writes row_ptr
__global__ void k_scan23(const int* __restrict__ tmp, const int* __restrict__ bsum,
                         int* __restrict__ row_ptr, int N) {
    __shared__ int s_off;
    int t = threadIdx.x;
    if (t < 64) {
        int cnt = blockIdx.x;  // number of preceding blocks
        int v = 0;
        for (int base = 0; base < cnt; base += 64)
            if (base + t < cnt) v += bsum[base + t];
        #pragma unroll
        for (int o = 32; o > 0; o >>= 1) v += __shfl_xor(v, o);
        if (t == 0) s_off = v;
    }
    __syncthreads();
    int i = blockIdx.x * 256 + t;
    if (i == 0) row_ptr[0] = 0;
    if (i < N) row_ptr[i + 1] = tmp[i] + s_off;
}

// ---------------- CSR scatter; packed {src, eid} int2 per slot ----------------
__global__ void k_csr(const int* __restrict__ src, const int* __restrict__ dst,
                      const int* __restrict__ row_ptr, int* __restrict__ cursor,
                      int2* __restrict__ csr_se, int E, int N) {
    int e = blockIdx.x * blockDim.x + threadIdx.x;
    if (e >= E) return;
    int d = clampi(dst[e], N);
    int pos = row_ptr[d] + atomicAdd(&cursor[d], 1);
    if (pos < E) csr_se[pos] = make_int2(clampi(src[e], N), e);
}

// ---------------- ONCE: a_ed for all 3 layers x 4 heads, CSR order ----------------
// planar output: aed[l][(E+N)][4]
__global__ __launch_bounds__(256) void k_ee(
    const float* __restrict__ edge_attr, const float* __restrict__ eW,
    const float* __restrict__ eB, const float* __restrict__ lin_eW,
    const float* __restrict__ att_e, const int2* __restrict__ csr_se,
    float* __restrict__ aed, int E, int N) {
    __shared__ float s_ew[256];    // [k*64+d]
    __shared__ float s_eb[64];
    __shared__ float s_wred[768];  // [l*256 + h*64 + d]
    size_t P4 = (size_t)(E + N) * 4;
    int t = threadIdx.x;
    s_ew[t] = eW[t];
    if (t < 64) s_eb[t] = eB[t];
    for (int idx = t; idx < 768; idx += 256) {
        int l = idx >> 8, hd = idx & 255, hh = hd >> 6, d = hd & 63;
        const float* We = lin_eW + (size_t)l * HD * 256;
        const float* ae = att_e + (size_t)l * 256;
        float acc = 0.f;
        for (int c = 0; c < 64; c++)
            acc = fmaf(We[d * 256 + hh * 64 + c], ae[hh * 64 + c], acc);
        s_wred[idx] = acc;
    }
    __syncthreads();
    int j0 = (blockIdx.x * 256 + t) * 4;
    if (j0 >= E) return;
    float4 a[4];
    int nv = 0;
    #pragma unroll
    for (int q = 0; q < 4; q++) {
        int j = j0 + q;
        if (j < E) {
            a[q] = *(const float4*)(edge_attr + (size_t)csr_se[j].y * 4);
            nv = q + 1;
        } else {
            a[q] = make_float4(0.f, 0.f, 0.f, 0.f);
        }
    }
    float acc[4][12];
    #pragma unroll
    for (int q = 0; q < 4; q++)
        #pragma unroll
        for (int m = 0; m < 12; m++) acc[q][m] = 0.f;
    for (int k = 0; k < HD; k++) {
        float e0 = s_ew[k], e1 = s_ew[64 + k], e2 = s_ew[128 + k], e3 = s_ew[192 + k];
        float eb = s_eb[k];
        float w[12];
        #pragma unroll
        for (int m = 0; m < 12; m++)
            w[m] = s_wred[(m >> 2) * 256 + (m & 3) * 64 + k];
        #pragma unroll
        for (int q = 0; q < 4; q++) {
            float v = fmaf(a[q].x, e0, fmaf(a[q].y, e1,
                      fmaf(a[q].z, e2, fmaf(a[q].w, e3, eb))));
            v = fmaxf(v, 0.f);
            #pragma unroll
            for (int m = 0; m < 12; m++) acc[q][m] = fmaf(v, w[m], acc[q][m]);
        }
    }
    #pragma unroll
    for (int q = 0; q < 4; q++) {
        if (q >= nv) break;
        #pragma unroll
        for (int l = 0; l < 3; l++) {
            *(float4*)(aed + l * P4 + (size_t)(j0 + q) * 4) =
                make_float4(acc[q][l * 4 + 0], acc[q][l * 4 + 1],
                            acc[q][l * 4 + 2], acc[q][l * 4 + 3]);
        }
    }
}

// ---------------- ONCE: self-loop a_ed rows by LINEARITY ----------------
__global__ void k_selfed(const int* __restrict__ row_ptr, float* __restrict__ aed,
                         int E, int N) {
    int n = blockIdx.x * blockDim.x + threadIdx.x;
    if (n >= N) return;
    size_t P4 = (size_t)(E + N) * 4;
    int r0 = row_ptr[n], r1 = row_ptr[n + 1];
    float acc[12];
    #pragma unroll
    for (int m = 0; m < 12; m++) acc[m] = 0.f;
    for (int j = r0; j < r1; j++) {
        #pragma unroll
        for (int l = 0; l < 3; l++) {
            float4 v = *(const float4*)(aed + l * P4 + (size_t)j * 4);
            acc[l * 4 + 0] += v.x; acc[l * 4 + 1] += v.y;
            acc[l * 4 + 2] += v.z; acc[l * 4 + 3] += v.w;
        }
    }
    float inv = 1.f / fmaxf((float)(r1 - r0), 1.f);
    #pragma unroll
    for (int l = 0; l < 3; l++) {
        *(float4*)(aed + l * P4 + (size_t)(E + n) * 4) =
            make_float4(acc[l * 4 + 0] * inv, acc[l * 4 + 1] * inv,
                        acc[l * 4 + 2] * inv, acc[l * 4 + 3] * inv);
    }
}

// ---------------- per-layer: xp = h@W, 8 nodes/block, broadcast h loads, NO LDS ----------
// All lanes of a wave read the same h line (L1 broadcast). NPB=8 keeps live VGPRs ~60
// (8 acc + 8x4 h + 4 W) -- the NPB=32 version spilled everything (VGPR_Count=28, 60us).
// xp is stored channel-major-interleaved: xp[n][cc*4+hh] so k_gat's per-edge row
// gather is two contiguous 16B loads per lane instead of four strided 8B loads.
#define NPB 8
__global__ __launch_bounds__(256) void k_xp(
    const float* __restrict__ h, const float* __restrict__ W,
    const float* __restrict__ asrc, const float* __restrict__ adst,
    u16* __restrict__ xp, float* __restrict__ a_s, float* __restrict__ a_d, int N) {
    int n0 = blockIdx.x * NPB;
    int c = threadIdx.x;
    int nlim = N - n0;  // >= 1
    const float* hp = h + (size_t)n0 * HD;
    float acc[NPB];
    #pragma unroll
    for (int k = 0; k < NPB; k++) acc[k] = 0.f;
    for (int d = 0; d < HD; d += 4) {
        float w0 = W[(d + 0) * 256 + c];
        float w1 = W[(d + 1) * 256 + c];
        float w2 = W[(d + 2) * 256 + c];
        float w3 = W[(d + 3) * 256 + c];
        #pragma unroll
        for (int k = 0; k < NPB; k++) {
            int kk = (k < nlim) ? k : 0;  // clamp for tail block
            float4 hv = *(const float4*)(hp + kk * HD + d);
            acc[k] = fmaf(hv.x, w0, acc[k]);
            acc[k] = fmaf(hv.y, w1, acc[k]);
            acc[k] = fmaf(hv.z, w2, acc[k]);
            acc[k] = fmaf(hv.w, w3, acc[k]);
        }
    }
    float as_ = asrc[c], ad_ = adst[c];
    int hh = c >> 6, cc = c & 63;
    #pragma unroll
    for (int k = 0; k < NPB; k++) {
        int nn = n0 + k;
        if (nn >= N) break;  // wave-uniform
        float ps = acc[k] * as_;
        float pd = acc[k] * ad_;
        #pragma unroll
        for (int o = 32; o > 0; o >>= 1) {
            ps += __shfl_xor(ps, o);
            pd += __shfl_xor(pd, o);
        }
        xp[(size_t)nn * 256 + cc * 4 + hh] = f2bf(acc[k]);
        if (cc == 0) { a_s[nn * 4 + hh] = ps; a_d[nn * 4 + hh] = pd; }
    }
}

// ---------------- per-layer GAT aggregate with fused attention weights ----------------
// (round-4 structure; only the xp row gather changed to match the interleaved layout:
//  lane p reads u16[p*16 .. p*16+15] = channels p*4..p*4+3 x heads 0..3 as 2x uint4.
//  Register envelope identical -- adding epilogue state here previously caused a
//  spill catastrophe, VGPR_Count 32, 47 -> 163us.)
__global__ __launch_bounds__(256) void k_gat(
    const u16* __restrict__ xp, const float* __restrict__ a_s,
    const float* __restrict__ a_d, const float* __restrict__ aedl,
    const int* __restrict__ row_ptr, const int2* __restrict__ csr_se,
    const float* __restrict__ convb, float* __restrict__ h_out, int N, int E) {
    int wave = threadIdx.x >> 6, lane = threadIdx.x & 63;
    int n = blockIdx.x * 4 + wave;
    if (n >= N) return;
    int g = lane >> 4, p = lane & 15;
    int r0 = row_ptr[n], r1 = row_ptr[n + 1];
    float4 ad4 = *(const float4*)(a_d + (size_t)n * 4);
    float a00 = 0.f, a01 = 0.f, a02 = 0.f, a03 = 0.f;
    float a10 = 0.f, a11 = 0.f, a12 = 0.f, a13 = 0.f;
    float a20 = 0.f, a21 = 0.f, a22 = 0.f, a23 = 0.f;
    float a30 = 0.f, a31 = 0.f, a32 = 0.f, a33 = 0.f;
    float d0 = 0.f, d1 = 0.f, d2 = 0.f, d3 = 0.f;
    if (g == 0) {
        // self loop: src = n
        float4 as4 = *(const float4*)(a_s + (size_t)n * 4);
        float4 p4 = *(const float4*)(aedl + (size_t)(E + n) * 4);
        float w0 = __expf(lrelu(as4.x + ad4.x + p4.x));
        float w1 = __expf(lrelu(as4.y + ad4.y + p4.y));
        float w2 = __expf(lrelu(as4.z + ad4.z + p4.z));
        float w3 = __expf(lrelu(as4.w + ad4.w + p4.w));
        const u16* row = xp + (size_t)n * 256 + p * 16;
        uint4 q0 = *(const uint4*)(row);
        uint4 q1 = *(const uint4*)(row + 8);
        d0 += w0; d1 += w1; d2 += w2; d3 += w3;
        a00 = fmaf(w0, bflo(q0.x), a00); a01 = fmaf(w0, bflo(q0.z), a01);
        a02 = fmaf(w0, bflo(q1.x), a02); a03 = fmaf(w0, bflo(q1.z), a03);
        a10 = fmaf(w1, bfhi(q0.x), a10); a11 = fmaf(w1, bfhi(q0.z), a11);
        a12 = fmaf(w1, bfhi(q1.x), a12); a13 = fmaf(w1, bfhi(q1.z), a13);
        a20 = fmaf(w2, bflo(q0.y), a20); a21 = fmaf(w2, bflo(q0.w), a21);
        a22 = fmaf(w2, bflo(q1.y), a22); a23 = fmaf(w2, bflo(q1.w), a23);
        a30 = fmaf(w3, bfhi(q0.y), a30); a31 = fmaf(w3, bfhi(q0.w), a31);
        a32 = fmaf(w3, bfhi(q1.y), a32); a33 = fmaf(w3, bfhi(q1.w), a33);
    }
    int j = r0 + g;
    int2 se = (j < r1) ? csr_se[j] : make_int2(0, 0);
    for (; j < r1; j += 4) {
        int jn = j + 4;
        int2 se_n = (jn < r1) ? csr_se[jn] : make_int2(0, 0);  // prefetch
        int s = se.x;
        float4 as4 = *(const float4*)(a_s + (size_t)s * 4);
        float4 p4 = *(const float4*)(aedl + (size_t)j * 4);
        float w0 = __expf(lrelu(as4.x + ad4.x + p4.x));
        float w1 = __expf(lrelu(as4.y + ad4.y + p4.y));
        float w2 = __expf(lrelu(as4.z + ad4.z + p4.z));
        float w3 = __expf(lrelu(as4.w + ad4.w + p4.w));
        const u16* row = xp + (size_t)s * 256 + p * 16;
        uint4 q0 = *(const uint4*)(row);
        uint4 q1 = *(const uint4*)(row + 8);
        d0 += w0; d1 += w1; d2 += w2; d3 += w3;
        a00 = fmaf(w0, bflo(q0.x), a00); a01 = fmaf(w0, bflo(q0.z), a01);
        a02 = fmaf(w0, bflo(q1.x), a02); a03 = fmaf(w0, bflo(q1.z), a03);
        a10 = fmaf(w1, bfhi(q0.x), a10); a11 = fmaf(w1, bfhi(q0.z), a11);
        a12 = fmaf(w1, bfhi(q1.x), a12); a13 = fmaf(w1, bfhi(q1.z), a13);
        a20 = fmaf(w2, bflo(q0.y), a20); a21 = fmaf(w2, bflo(q0.w), a21);
        a22 = fmaf(w2, bflo(q1.y), a22); a23 = fmaf(w2, bflo(q1.w), a23);
        a30 = fmaf(w3, bfhi(q0.y), a30); a31 = fmaf(w3, bfhi(q0.w), a31);
        a32 = fmaf(w3, bfhi(q1.y), a32); a33 = fmaf(w3, bfhi(q1.w), a33);
        se = se_n;
    }
    d0 += __shfl_xor(d0, 16); d0 += __shfl_xor(d0, 32);
    d1 += __shfl_xor(d1, 16); d1 += __shfl_xor(d1, 32);
    d2 += __shfl_xor(d2, 16); d2 += __shfl_xor(d2, 32);
    d3 += __shfl_xor(d3, 16); d3 += __shfl_xor(d3, 32);
    float i0 = 1.f / d0, i1 = 1.f / d1, i2 = 1.f / d2, i3 = 1.f / d3;
    float m0 = a00 * i0 + a10 * i1 + a20 * i2 + a30 * i3;
    float m1 = a01 * i0 + a11 * i1 + a21 * i2 + a31 * i3;
    float m2 = a02 * i0 + a12 * i1 + a22 * i2 + a32 * i3;
    float m3 = a03 * i0 + a13 * i1 + a23 * i2 + a33 * i3;
    m0 += __shfl_xor(m0, 16); m0 += __shfl_xor(m0, 32);
    m1 += __shfl_xor(m1, 16); m1 += __shfl_xor(m1, 32);
    m2 += __shfl_xor(m2, 16); m2 += __shfl_xor(m2, 32);
    m3 += __shfl_xor(m3, 16); m3 += __shfl_xor(m3, 32);
    if (lane < 16) {
        int c = p * 4;
        h_out[(size_t)n * HD + c + 0] = fmaxf(0.25f * m0 + convb[c + 0], 0.f);
        h_out[(size_t)n * HD + c + 1] = fmaxf(0.25f * m1 + convb[c + 1], 0.f);
        h_out[(size_t)n * HD + c + 2] = fmaxf(0.25f * m2 + convb[c + 2], 0.f);
        h_out[(size_t)n * HD + c + 3] = fmaxf(0.25f * m3 + convb[c + 3], 0.f);
    }
}

// ---------------- global pool: batch is SORTED -> segmented reduce (round-1 proven) -------
// node-parallel atomic version measured ~45us (625-way contention/address); this one
// does ~16K atomics total.
#define PCHUNK 8
__global__ void k_pool(const float* __restrict__ h, const int* __restrict__ batch,
                       float* __restrict__ pooled, int N, int B) {
    int b = blockIdx.x / PCHUNK, q = blockIdx.x % PCHUNK;
    __shared__ int sb[2];
    __shared__ float sred[256];
    int t = threadIdx.x;
    if (t == 0 || t == 64) {
        int target = b + (t ? 1 : 0);
        int lo = 0, hi = N;
        while (lo < hi) {
            int m = (lo + hi) >> 1;
            if (batch[m] < target) lo = m + 1; else hi = m;
        }
        sb[t ? 1 : 0] = lo;
    }
    __syncthreads();
    int start = sb[0], end = sb[1];
    int len = end - start;
    int c0 = start + (int)(((long long)len * q) / PCHUNK);
    int c1 = start + (int)(((long long)len * (q + 1)) / PCHUNK);
    int c = t & 63, r = t >> 6;
    float acc = 0.f;
    for (int nidx = c0 + r; nidx < c1; nidx += 4)
        acc += h[(size_t)nidx * HD + c];
    sred[t] = acc;
    __syncthreads();
    if (t < 64) {
        float v = sred[t] + sred[64 + t] + sred[128 + t] + sred[192 + t];
        if (v != 0.f) atomicAdd(&pooled[b * HD + c], v);
    }
}

// ---------------- final MLP: B blocks x 64 threads; len via binary search ----------------
__global__ void k_mlp(const float* __restrict__ u, const float* __restrict__ gW,
                      const float* __restrict__ gb, const float* __restrict__ pooled,
                      const int* __restrict__ batch, const float* __restrict__ f1W,
                      const float* __restrict__ f1b, const float* __restrict__ f2W,
                      const float* __restrict__ f2b, float* __restrict__ out,
                      int N, int B) {
    __shared__ float z[2 * HD];
    __shared__ float z1s[HD];
    __shared__ int sb[2];
    int b = blockIdx.x, t = threadIdx.x;  // 64 threads
    if (t < 2) {
        int target = b + t;
        int lo = 0, hi = N;
        while (lo < hi) {
            int m = (lo + hi) >> 1;
            if (batch[m] < target) lo = m + 1; else hi = m;
        }
        sb[t] = lo;
    }
    float acc = gb[t];
    for (int k = 0; k < 10; k++) acc = fmaf(u[b * 10 + k], gW[k * HD + t], acc);
    z[HD + t] = fmaxf(acc, 0.f);
    __syncthreads();
    float invc = 1.f / fmaxf((float)(sb[1] - sb[0]), 1.f);
    z[t] = pooled[b * HD + t] * invc;
    __syncthreads();
    float a1 = f1b[t];
    for (int k = 0; k < 2 * HD; k++) a1 = fmaf(z[k], f1W[k * HD + t], a1);
    z1s[t] = fmaxf(a1, 0.f);
    __syncthreads();
    if (t < 2) {
        float o = f2b[t];
        for (int k = 0; k < HD; k++) o = fmaf(z1s[k], f2W[k * 2 + t], o);
        out[b * 2 + t] = o;
    }
}

extern "C" void kernel_launch(void* const* d_in, const int* in_sizes, int n_in,
                              void* d_out, int out_size, void* d_ws, size_t ws_size,
                              hipStream_t stream) {
    const float* x         = (const float*)d_in[0];
    const int*   ei        = (const int*)d_in[1];
    const float* edge_attr = (const float*)d_in[2];
    const float* u         = (const float*)d_in[3];
    const int*   batch     = (const int*)d_in[4];
    const float* node_W    = (const float*)d_in[5];
    const float* node_b    = (const float*)d_in[6];
    const float* eemb_W    = (const float*)d_in[7];
    const float* eemb_b    = (const float*)d_in[8];
    const float* lin_W     = (const float*)d_in[9];
    const float* att_src   = (const float*)d_in[10];
    const float* att_dst   = (const float*)d_in[11];
    const float* lin_eW    = (const float*)d_in[12];
    const float* att_e     = (const float*)d_in[13];
    const float* conv_b    = (const float*)d_in[14];
    const float* gW        = (const float*)d_in[15];
    const float* gb        = (const float*)d_in[16];
    const float* f1W       = (const float*)d_in[17];
    const float* f1b       = (const float*)d_in[18];
    const float* f2W       = (const float*)d_in[19];
    const float* f2b       = (const float*)d_in[20];

    const int N = in_sizes[0] / 3;
    const int E = in_sizes[2] / 4;
    const int B = in_sizes[3] / 10;
    const int* src = ei;
    const int* dst = ei + E;
    const int NB = (N + 255) / 256;   // scan blocks
    const size_t P4 = (size_t)(E + N) * 4;  // aed plane stride (floats)

    // workspace carve (fp32, then bf16, then ints; all region sizes keep 16B alignment)
    float* wsf = (float*)d_ws;
    float* h       = wsf;              wsf += (size_t)N * HD;
    float* a_s     = wsf;              wsf += (size_t)N * 4;
    float* a_d     = wsf;              wsf += (size_t)N * 4;
    float* aed     = wsf;              wsf += 3 * P4;
    float* pooled  = wsf;              wsf += (size_t)B * HD;
    u16* xp = (u16*)wsf;               wsf += (size_t)N * 128;   // N*256 bf16
    int* wsi = (int*)wsf;
    int2* csr_se = (int2*)wsi;         wsi += 2 * (size_t)E;     // 8B-aligned
    int* deg     = wsi;                wsi += N;
    int* row_ptr = wsi;                wsi += N + 1;
    int* cursor  = wsi;                wsi += N;
    int* tmp     = wsi;                wsi += N;
    int* bsum    = wsi;                wsi += NB + 1;

    k_init<<<(N * HD + 255) / 256, 256, 0, stream>>>(x, node_W, node_b, h,
                                                     deg, cursor, pooled, N, B);
    k_deg<<<(E + 255) / 256, 256, 0, stream>>>(dst, deg, E, N);
    k_scan1<<<NB, 256, 0, stream>>>(deg, tmp, bsum, N);
    k_scan23<<<NB, 256, 0, stream>>>(tmp, bsum, row_ptr, N);
    k_csr<<<(E + 255) / 256, 256, 0, stream>>>(src, dst, row_ptr, cursor,
                                               csr_se, E, N);
    k_ee<<<(E + 1023) / 1024, 256, 0, stream>>>(edge_attr, eemb_W, eemb_b, lin_eW, att_e,
                                                csr_se, aed, E, N);
    k_selfed<<<NB, 256, 0, stream>>>(row_ptr, aed, E, N);
    for (int i = 0; i < 3; i++) {
        k_xp<<<(N + NPB - 1) / NPB, 256, 0, stream>>>(h, lin_W + (size_t)i * HD * 256,
                                                      att_src + (size_t)i * 256,
                                                      att_dst + (size_t)i * 256,
                                                      xp, a_s, a_d, N);
        k_gat<<<(N + 3) / 4, 256, 0, stream>>>(xp, a_s, a_d, aed + (size_t)i * P4,
                                               row_ptr, csr_se,
                                               conv_b + (size_t)i * HD, h, N, E);
    }
    k_pool<<<B * PCHUNK, 256, 0, stream>>>(h, batch, pooled, N, B);
    k_mlp<<<B, 64, 0, stream>>>(u, gW, gb, pooled, batch, f1W, f1b, f2W, f2b,
                                (float*)d_out, N, B);
}

// Round 9
// 369.063 us; speedup vs baseline: 1.4355x; 1.0080x over previous
//
#include <hip/hip_runtime.h>
#include <hip/hip_bf16.h>

#define HD 64

typedef unsigned short u16;

__device__ __forceinline__ float lrelu(float x) { return x > 0.f ? x : 0.2f * x; }
__device__ __forceinline__ int clampi(int v, int maxv) {
    return v < 0 ? 0 : (v >= maxv ? maxv - 1 : v);
}
__device__ __forceinline__ float bf2f(u16 u) {
    return __uint_as_float(((unsigned int)u) << 16);
}
// extract bf16 pair packed in a u32 (little-endian): lo = bits[15:0], hi = bits[31:16]
__device__ __forceinline__ float bflo(unsigned int u) { return __uint_as_float(u << 16); }
__device__ __forceinline__ float bfhi(unsigned int u) { return __uint_as_float(u & 0xffff0000u); }
// round-to-nearest-even fp32 -> bf16 (bit-level; inputs are finite)
__device__ __forceinline__ u16 f2bf(float f) {
    unsigned int u = __float_as_uint(f);
    unsigned int lsb = (u >> 16) & 1u;
    u += 0x7fffu + lsb;
    return (u16)(u >> 16);
}

// ---------------- init (zero deg/cursor/pooled) + node embedding + Ws/Wd precompute -------
// wsd[l][idx][d] with idx = h*2+sel (sel 0=src,1=dst):
//   wsd = sum_c W_l[d][h*64+c] * att_{src|dst}[l][h][c]
// so a_s[n,h] = sum_d h[n,d]*wsd[l][h*2+0][d]  (linearity of the attention dot).
__global__ void k_init(const float* __restrict__ x, const float* __restrict__ W,
                       const float* __restrict__ b, float* __restrict__ h,
                       const float* __restrict__ lin_W, const float* __restrict__ att_src,
                       const float* __restrict__ att_dst, float* __restrict__ wsd,
                       int* deg, int* cursor, float* pooled, int N, int B) {
    int i = blockIdx.x * blockDim.x + threadIdx.x;
    if (i < N) { deg[i] = 0; cursor[i] = 0; }
    if (i < B * HD) pooled[i] = 0.f;
    if (i < 3 * 512) {
        int l = i >> 9, r = i & 511;
        int idx = r >> 6, d = r & 63;
        int hh = idx >> 1, sel = idx & 1;
        const float* att = (sel ? att_dst : att_src) + l * 256 + hh * 64;
        const float* Wrow = lin_W + (size_t)l * HD * 256 + d * 256 + hh * 64;
        float acc = 0.f;
        for (int c = 0; c < 64; c++) acc = fmaf(Wrow[c], att[c], acc);
        wsd[(l << 9) + (idx << 6) + d] = acc;
    }
    if (i < N * HD) {
        int n = i >> 6, c = i & 63;
        float acc = b[c];
        acc = fmaf(x[n * 3 + 0], W[0 * HD + c], acc);
        acc = fmaf(x[n * 3 + 1], W[1 * HD + c], acc);
        acc = fmaf(x[n * 3 + 2], W[2 * HD + c], acc);
        h[i] = fmaxf(acc, 0.f);
    }
}

// ---------------- degree histogram over dst ----------------
__global__ void k_deg(const int* __restrict__ dst, int* __restrict__ deg, int E, int N) {
    int e = blockIdx.x * blockDim.x + threadIdx.x;
    if (e < E) atomicAdd(&deg[clampi(dst[e], N)], 1);
}

// ---------------- hierarchical scan (2 kernels) ----------------
__global__ void k_scan1(const int* __restrict__ deg, int* __restrict__ tmp,
                        int* __restrict__ bsum, int N) {
    __shared__ int s[256];
    int tid = threadIdx.x;
    int i = blockIdx.x * 256 + tid;
    int v = (i < N) ? deg[i] : 0;
    s[tid] = v;
    __syncthreads();
    for (int off = 1; off < 256; off <<= 1) {
        int t = (tid >= off) ? s[tid - off] : 0;
        __syncthreads();
        s[tid] += t;
        __syncthreads();
    }
    if (i < N) tmp[i] = s[tid];
    if (tid == 255) bsum[blockIdx.x] = s[255];
}
// each block: wave 0 redundantly computes exclusive prefix of bsum[0..bid), then writes row_ptr
__global__ void k_scan23(const int* __restrict__ tmp, const int* __restrict__ bsum,
                         int* __restrict__ row_ptr, int N) {
    __shared__ int s_off;
    int t = threadIdx.x;
    if (t < 64) {
        int cnt = blockIdx.x;  // number of preceding blocks
        int v = 0;
        for (int base = 0; base < cnt; base += 64)
            if (base + t < cnt) v += bsum[base + t];
        #pragma unroll
        for (int o = 32; o > 0; o >>= 1) v += __shfl_xor(v, o);
        if (t == 0) s_off = v;
    }
    __syncthreads();
    int i = blockIdx.x * 256 + t;
    if (i == 0) row_ptr[0] = 0;
    if (i < N) row_ptr[i + 1] = tmp[i] + s_off;
}

// ---------------- CSR scatter; packed {src, eid} int2 per slot ----------------
__global__ void k_csr(const int* __restrict__ src, const int* __restrict__ dst,
                      const int* __restrict__ row_ptr, int* __restrict__ cursor,
                      int2* __restrict__ csr_se, int E, int N) {
    int e = blockIdx.x * blockDim.x + threadIdx.x;
    if (e >= E) return;
    int d = clampi(dst[e], N);
    int pos = row_ptr[d] + atomicAdd(&cursor[d], 1);
    if (pos < E) csr_se[pos] = make_int2(clampi(src[e], N), e);
}

// ---------------- ONCE: a_ed for all 3 layers x 4 heads, CSR order ----------------
// planar output: aed[l][(E+N)][4]
__global__ __launch_bounds__(256) void k_ee(
    const float* __restrict__ edge_attr, const float* __restrict__ eW,
    const float* __restrict__ eB, const float* __restrict__ lin_eW,
    const float* __restrict__ att_e, const int2* __restrict__ csr_se,
    float* __restrict__ aed, int E, int N) {
    __shared__ float s_ew[256];    // [k*64+d]
    __shared__ float s_eb[64];
    __shared__ float s_wred[768];  // [l*256 + h*64 + d]
    size_t P4 = (size_t)(E + N) * 4;
    int t = threadIdx.x;
    s_ew[t] = eW[t];
    if (t < 64) s_eb[t] = eB[t];
    for (int idx = t; idx < 768; idx += 256) {
        int l = idx >> 8, hd = idx & 255, hh = hd >> 6, d = hd & 63;
        const float* We = lin_eW + (size_t)l * HD * 256;
        const float* ae = att_e + (size_t)l * 256;
        float acc = 0.f;
        for (int c = 0; c < 64; c++)
            acc = fmaf(We[d * 256 + hh * 64 + c], ae[hh * 64 + c], acc);
        s_wred[idx] = acc;
    }
    __syncthreads();
    int j0 = (blockIdx.x * 256 + t) * 4;
    if (j0 >= E) return;
    float4 a[4];
    int nv = 0;
    #pragma unroll
    for (int q = 0; q < 4; q++) {
        int j = j0 + q;
        if (j < E) {
            a[q] = *(const float4*)(edge_attr + (size_t)csr_se[j].y * 4);
            nv = q + 1;
        } else {
            a[q] = make_float4(0.f, 0.f, 0.f, 0.f);
        }
    }
    float acc[4][12];
    #pragma unroll
    for (int q = 0; q < 4; q++)
        #pragma unroll
        for (int m = 0; m < 12; m++) acc[q][m] = 0.f;
    for (int k = 0; k < HD; k++) {
        float e0 = s_ew[k], e1 = s_ew[64 + k], e2 = s_ew[128 + k], e3 = s_ew[192 + k];
        float eb = s_eb[k];
        float w[12];
        #pragma unroll
        for (int m = 0; m < 12; m++)
            w[m] = s_wred[(m >> 2) * 256 + (m & 3) * 64 + k];
        #pragma unroll
        for (int q = 0; q < 4; q++) {
            float v = fmaf(a[q].x, e0, fmaf(a[q].y, e1,
                      fmaf(a[q].z, e2, fmaf(a[q].w, e3, eb))));
            v = fmaxf(v, 0.f);
            #pragma unroll
            for (int m = 0; m < 12; m++) acc[q][m] = fmaf(v, w[m], acc[q][m]);
        }
    }
    #pragma unroll
    for (int q = 0; q < 4; q++) {
        if (q >= nv) break;
        #pragma unroll
        for (int l = 0; l < 3; l++) {
            *(float4*)(aed + l * P4 + (size_t)(j0 + q) * 4) =
                make_float4(acc[q][l * 4 + 0], acc[q][l * 4 + 1],
                            acc[q][l * 4 + 2], acc[q][l * 4 + 3]);
        }
    }
}

// ---------------- ONCE: self-loop a_ed rows by LINEARITY ----------------
__global__ void k_selfed(const int* __restrict__ row_ptr, float* __restrict__ aed,
                         int E, int N) {
    int n = blockIdx.x * blockDim.x + threadIdx.x;
    if (n >= N) return;
    size_t P4 = (size_t)(E + N) * 4;
    int r0 = row_ptr[n], r1 = row_ptr[n + 1];
    float acc[12];
    #pragma unroll
    for (int m = 0; m < 12; m++) acc[m] = 0.f;
    for (int j = r0; j < r1; j++) {
        #pragma unroll
        for (int l = 0; l < 3; l++) {
            float4 v = *(const float4*)(aed + l * P4 + (size_t)j * 4);
            acc[l * 4 + 0] += v.x; acc[l * 4 + 1] += v.y;
            acc[l * 4 + 2] += v.z; acc[l * 4 + 3] += v.w;
        }
    }
    float inv = 1.f / fmaxf((float)(r1 - r0), 1.f);
    #pragma unroll
    for (int l = 0; l < 3; l++) {
        *(float4*)(aed + l * P4 + (size_t)(E + n) * 4) =
            make_float4(acc[l * 4 + 0] * inv, acc[l * 4 + 1] * inv,
                        acc[l * 4 + 2] * inv, acc[l * 4 + 3] * inv);
    }
}

// ---------------- per-layer: xp = h@W, 8 nodes/block, broadcast h loads, NO LDS ----------
// NPB=8 keeps live VGPRs ~60 (NPB=32 spilled everything: VGPR_Count=28, 60us).
// xp stored channel-major-interleaved xp[n][cc*4+hh] (k_gat reads 2x uint4 per lane).
// a_s/a_d epilogue: NO shuffles -- a_s[n,h] = h-row dot wsd[l][h*2+0] (64x4 matrix
// precomputed in k_init by linearity); 64 threads each compute one value.
// The old epilogue's 96 shfl_xor per wave was ~comparable to the whole FMA body.
#define NPB 8
__global__ __launch_bounds__(256) void k_xp(
    const float* __restrict__ h, const float* __restrict__ W,
    const float* __restrict__ wsdl, u16* __restrict__ xp,
    float* __restrict__ a_s, float* __restrict__ a_d, int N) {
    int n0 = blockIdx.x * NPB;
    int c = threadIdx.x;
    int nlim = N - n0;  // >= 1
    const float* hp = h + (size_t)n0 * HD;
    float acc[NPB];
    #pragma unroll
    for (int k = 0; k < NPB; k++) acc[k] = 0.f;
    for (int d = 0; d < HD; d += 4) {
        float w0 = W[(d + 0) * 256 + c];
        float w1 = W[(d + 1) * 256 + c];
        float w2 = W[(d + 2) * 256 + c];
        float w3 = W[(d + 3) * 256 + c];
        #pragma unroll
        for (int k = 0; k < NPB; k++) {
            int kk = (k < nlim) ? k : 0;  // clamp for tail block
            float4 hv = *(const float4*)(hp + kk * HD + d);
            acc[k] = fmaf(hv.x, w0, acc[k]);
            acc[k] = fmaf(hv.y, w1, acc[k]);
            acc[k] = fmaf(hv.z, w2, acc[k]);
            acc[k] = fmaf(hv.w, w3, acc[k]);
        }
    }
    int hh = c >> 6, cc = c & 63;
    #pragma unroll
    for (int k = 0; k < NPB; k++) {
        int nn = n0 + k;
        if (nn >= N) break;  // wave-uniform
        xp[(size_t)nn * 256 + cc * 4 + hh] = f2bf(acc[k]);
    }
    // a_s/a_d: thread t<64 handles (node t>>3, idx t&7); idx = h*2+sel
    if (c < 64) {
        int k = c >> 3, idx = c & 7;
        int nn = n0 + k;
        if (nn < N) {
            const float* hr = hp + k * HD;
            const float* wp = wsdl + (idx << 6);
            float a = 0.f;
            for (int d = 0; d < HD; d += 4) {
                float4 hv = *(const float4*)(hr + d);
                float4 wv = *(const float4*)(wp + d);
                a = fmaf(hv.x, wv.x, a);
                a = fmaf(hv.y, wv.y, a);
                a = fmaf(hv.z, wv.z, a);
                a = fmaf(hv.w, wv.w, a);
            }
            int hd = idx >> 1, sel = idx & 1;
            if (sel) a_d[nn * 4 + hd] = a;
            else     a_s[nn * 4 + hd] = a;
        }
    }
}

// ---------------- per-layer GAT aggregate with fused attention weights ----------------
// (structure frozen: adding epilogue state here previously caused a spill catastrophe,
//  VGPR_Count 32, 47 -> 163us)
__global__ __launch_bounds__(256) void k_gat(
    const u16* __restrict__ xp, const float* __restrict__ a_s,
    const float* __restrict__ a_d, const float* __restrict__ aedl,
    const int* __restrict__ row_ptr, const int2* __restrict__ csr_se,
    const float* __restrict__ convb, float* __restrict__ h_out, int N, int E) {
    int wave = threadIdx.x >> 6, lane = threadIdx.x & 63;
    int n = blockIdx.x * 4 + wave;
    if (n >= N) return;
    int g = lane >> 4, p = lane & 15;
    int r0 = row_ptr[n], r1 = row_ptr[n + 1];
    float4 ad4 = *(const float4*)(a_d + (size_t)n * 4);
    float a00 = 0.f, a01 = 0.f, a02 = 0.f, a03 = 0.f;
    float a10 = 0.f, a11 = 0.f, a12 = 0.f, a13 = 0.f;
    float a20 = 0.f, a21 = 0.f, a22 = 0.f, a23 = 0.f;
    float a30 = 0.f, a31 = 0.f, a32 = 0.f, a33 = 0.f;
    float d0 = 0.f, d1 = 0.f, d2 = 0.f, d3 = 0.f;
    if (g == 0) {
        // self loop: src = n
        float4 as4 = *(const float4*)(a_s + (size_t)n * 4);
        float4 p4 = *(const float4*)(aedl + (size_t)(E + n) * 4);
        float w0 = __expf(lrelu(as4.x + ad4.x + p4.x));
        float w1 = __expf(lrelu(as4.y + ad4.y + p4.y));
        float w2 = __expf(lrelu(as4.z + ad4.z + p4.z));
        float w3 = __expf(lrelu(as4.w + ad4.w + p4.w));
        const u16* row = xp + (size_t)n * 256 + p * 16;
        uint4 q0 = *(const uint4*)(row);
        uint4 q1 = *(const uint4*)(row + 8);
        d0 += w0; d1 += w1; d2 += w2; d3 += w3;
        a00 = fmaf(w0, bflo(q0.x), a00); a01 = fmaf(w0, bflo(q0.z), a01);
        a02 = fmaf(w0, bflo(q1.x), a02); a03 = fmaf(w0, bflo(q1.z), a03);
        a10 = fmaf(w1, bfhi(q0.x), a10); a11 = fmaf(w1, bfhi(q0.z), a11);
        a12 = fmaf(w1, bfhi(q1.x), a12); a13 = fmaf(w1, bfhi(q1.z), a13);
        a20 = fmaf(w2, bflo(q0.y), a20); a21 = fmaf(w2, bflo(q0.w), a21);
        a22 = fmaf(w2, bflo(q1.y), a22); a23 = fmaf(w2, bflo(q1.w), a23);
        a30 = fmaf(w3, bfhi(q0.y), a30); a31 = fmaf(w3, bfhi(q0.w), a31);
        a32 = fmaf(w3, bfhi(q1.y), a32); a33 = fmaf(w3, bfhi(q1.w), a33);
    }
    int j = r0 + g;
    int2 se = (j < r1) ? csr_se[j] : make_int2(0, 0);
    for (; j < r1; j += 4) {
        int jn = j + 4;
        int2 se_n = (jn < r1) ? csr_se[jn] : make_int2(0, 0);  // prefetch
        int s = se.x;
        float4 as4 = *(const float4*)(a_s + (size_t)s * 4);
        float4 p4 = *(const float4*)(aedl + (size_t)j * 4);
        float w0 = __expf(lrelu(as4.x + ad4.x + p4.x));
        float w1 = __expf(lrelu(as4.y + ad4.y + p4.y));
        float w2 = __expf(lrelu(as4.z + ad4.z + p4.z));
        float w3 = __expf(lrelu(as4.w + ad4.w + p4.w));
        const u16* row = xp + (size_t)s * 256 + p * 16;
        uint4 q0 = *(const uint4*)(row);
        uint4 q1 = *(const uint4*)(row + 8);
        d0 += w0; d1 += w1; d2 += w2; d3 += w3;
        a00 = fmaf(w0, bflo(q0.x), a00); a01 = fmaf(w0, bflo(q0.z), a01);
        a02 = fmaf(w0, bflo(q1.x), a02); a03 = fmaf(w0, bflo(q1.z), a03);
        a10 = fmaf(w1, bfhi(q0.x), a10); a11 = fmaf(w1, bfhi(q0.z), a11);
        a12 = fmaf(w1, bfhi(q1.x), a12); a13 = fmaf(w1, bfhi(q1.z), a13);
        a20 = fmaf(w2, bflo(q0.y), a20); a21 = fmaf(w2, bflo(q0.w), a21);
        a22 = fmaf(w2, bflo(q1.y), a22); a23 = fmaf(w2, bflo(q1.w), a23);
        a30 = fmaf(w3, bfhi(q0.y), a30); a31 = fmaf(w3, bfhi(q0.w), a31);
        a32 = fmaf(w3, bfhi(q1.y), a32); a33 = fmaf(w3, bfhi(q1.w), a33);
        se = se_n;
    }
    d0 += __shfl_xor(d0, 16); d0 += __shfl_xor(d0, 32);
    d1 += __shfl_xor(d1, 16); d1 += __shfl_xor(d1, 32);
    d2 += __shfl_xor(d2, 16); d2 += __shfl_xor(d2, 32);
    d3 += __shfl_xor(d3, 16); d3 += __shfl_xor(d3, 32);
    float i0 = 1.f / d0, i1 = 1.f / d1, i2 = 1.f / d2, i3 = 1.f / d3;
    float m0 = a00 * i0 + a10 * i1 + a20 * i2 + a30 * i3;
    float m1 = a01 * i0 + a11 * i1 + a21 * i2 + a31 * i3;
    float m2 = a02 * i0 + a12 * i1 + a22 * i2 + a32 * i3;
    float m3 = a03 * i0 + a13 * i1 + a23 * i2 + a33 * i3;
    m0 += __shfl_xor(m0, 16); m0 += __shfl_xor(m0, 32);
    m1 += __shfl_xor(m1, 16); m1 += __shfl_xor(m1, 32);
    m2 += __shfl_xor(m2, 16); m2 += __shfl_xor(m2, 32);
    m3 += __shfl_xor(m3, 16); m3 += __shfl_xor(m3, 32);
    if (lane < 16) {
        int c = p * 4;
        h_out[(size_t)n * HD + c + 0] = fmaxf(0.25f * m0 + convb[c + 0], 0.f);
        h_out[(size_t)n * HD + c + 1] = fmaxf(0.25f * m1 + convb[c + 1], 0.f);
        h_out[(size_t)n * HD + c + 2] = fmaxf(0.25f * m2 + convb[c + 2], 0.f);
        h_out[(size_t)n * HD + c + 3] = fmaxf(0.25f * m3 + convb[c + 3], 0.f);
    }
}

// ---------------- global pool: batch is SORTED -> segmented reduce (round-1 proven) -------
#define PCHUNK 8
__global__ void k_pool(const float* __restrict__ h, const int* __restrict__ batch,
                       float* __restrict__ pooled, int N, int B) {
    int b = blockIdx.x / PCHUNK, q = blockIdx.x % PCHUNK;
    __shared__ int sb[2];
    __shared__ float sred[256];
    int t = threadIdx.x;
    if (t == 0 || t == 64) {
        int target = b + (t ? 1 : 0);
        int lo = 0, hi = N;
        while (lo < hi) {
            int m = (lo + hi) >> 1;
            if (batch[m] < target) lo = m + 1; else hi = m;
        }
        sb[t ? 1 : 0] = lo;
    }
    __syncthreads();
    int start = sb[0], end = sb[1];
    int len = end - start;
    int c0 = start + (int)(((long long)len * q) / PCHUNK);
    int c1 = start + (int)(((long long)len * (q + 1)) / PCHUNK);
    int c = t & 63, r = t >> 6;
    float acc = 0.f;
    for (int nidx = c0 + r; nidx < c1; nidx += 4)
        acc += h[(size_t)nidx * HD + c];
    sred[t] = acc;
    __syncthreads();
    if (t < 64) {
        float v = sred[t] + sred[64 + t] + sred[128 + t] + sred[192 + t];
        if (v != 0.f) atomicAdd(&pooled[b * HD + c], v);
    }
}

// ---------------- final MLP: B blocks x 64 threads; len via binary search ----------------
__global__ void k_mlp(const float* __restrict__ u, const float* __restrict__ gW,
                      const float* __restrict__ gb, const float* __restrict__ pooled,
                      const int* __restrict__ batch, const float* __restrict__ f1W,
                      const float* __restrict__ f1b, const float* __restrict__ f2W,
                      const float* __restrict__ f2b, float* __restrict__ out,
                      int N, int B) {
    __shared__ float z[2 * HD];
    __shared__ float z1s[HD];
    __shared__ int sb[2];
    int b = blockIdx.x, t = threadIdx.x;  // 64 threads
    if (t < 2) {
        int target = b + t;
        int lo = 0, hi = N;
        while (lo < hi) {
            int m = (lo + hi) >> 1;
            if (batch[m] < target) lo = m + 1; else hi = m;
        }
        sb[t] = lo;
    }
    float acc = gb[t];
    for (int k = 0; k < 10; k++) acc = fmaf(u[b * 10 + k], gW[k * HD + t], acc);
    z[HD + t] = fmaxf(acc, 0.f);
    __syncthreads();
    float invc = 1.f / fmaxf((float)(sb[1] - sb[0]), 1.f);
    z[t] = pooled[b * HD + t] * invc;
    __syncthreads();
    float a1 = f1b[t];
    for (int k = 0; k < 2 * HD; k++) a1 = fmaf(z[k], f1W[k * HD + t], a1);
    z1s[t] = fmaxf(a1, 0.f);
    __syncthreads();
    if (t < 2) {
        float o = f2b[t];
        for (int k = 0; k < HD; k++) o = fmaf(z1s[k], f2W[k * 2 + t], o);
        out[b * 2 + t] = o;
    }
}

extern "C" void kernel_launch(void* const* d_in, const int* in_sizes, int n_in,
                              void* d_out, int out_size, void* d_ws, size_t ws_size,
                              hipStream_t stream) {
    const float* x         = (const float*)d_in[0];
    const int*   ei        = (const int*)d_in[1];
    const float* edge_attr = (const float*)d_in[2];
    const float* u         = (const float*)d_in[3];
    const int*   batch     = (const int*)d_in[4];
    const float* node_W    = (const float*)d_in[5];
    const float* node_b    = (const float*)d_in[6];
    const float* eemb_W    = (const float*)d_in[7];
    const float* eemb_b    = (const float*)d_in[8];
    const float* lin_W     = (const float*)d_in[9];
    const float* att_src   = (const float*)d_in[10];
    const float* att_dst   = (const float*)d_in[11];
    const float* lin_eW    = (const float*)d_in[12];
    const float* att_e     = (const float*)d_in[13];
    const float* conv_b    = (const float*)d_in[14];
    const float* gW        = (const float*)d_in[15];
    const float* gb        = (const float*)d_in[16];
    const float* f1W       = (const float*)d_in[17];
    const float* f1b       = (const float*)d_in[18];
    const float* f2W       = (const float*)d_in[19];
    const float* f2b       = (const float*)d_in[20];

    const int N = in_sizes[0] / 3;
    const int E = in_sizes[2] / 4;
    const int B = in_sizes[3] / 10;
    const int* src = ei;
    const int* dst = ei + E;
    const int NB = (N + 255) / 256;   // scan blocks
    const size_t P4 = (size_t)(E + N) * 4;  // aed plane stride (floats)

    // workspace carve (fp32, then bf16, then ints; float counts before xp are all
    // multiples of 4 -> xp stays 16B aligned for the uint4 reads)
    float* wsf = (float*)d_ws;
    float* h       = wsf;              wsf += (size_t)N * HD;
    float* a_s     = wsf;              wsf += (size_t)N * 4;
    float* a_d     = wsf;              wsf += (size_t)N * 4;
    float* aed     = wsf;              wsf += 3 * P4;
    float* pooled  = wsf;              wsf += (size_t)B * HD;
    float* wsd     = wsf;              wsf += 3 * 512;          // Ws/Wd tables
    u16* xp = (u16*)wsf;               wsf += (size_t)N * 128;  // N*256 bf16
    int* wsi = (int*)wsf;
    int2* csr_se = (int2*)wsi;         wsi += 2 * (size_t)E;    // 8B-aligned
    int* deg     = wsi;                wsi += N;
    int* row_ptr = wsi;                wsi += N + 1;
    int* cursor  = wsi;                wsi += N;
    int* tmp     = wsi;                wsi += N;
    int* bsum    = wsi;                wsi += NB + 1;

    k_init<<<(N * HD + 255) / 256, 256, 0, stream>>>(x, node_W, node_b, h,
                                                     lin_W, att_src, att_dst, wsd,
                                                     deg, cursor, pooled, N, B);
    k_deg<<<(E + 255) / 256, 256, 0, stream>>>(dst, deg, E, N);
    k_scan1<<<NB, 256, 0, stream>>>(deg, tmp, bsum, N);
    k_scan23<<<NB, 256, 0, stream>>>(tmp, bsum, row_ptr, N);
    k_csr<<<(E + 255) / 256, 256, 0, stream>>>(src, dst, row_ptr, cursor,
                                               csr_se, E, N);
    k_ee<<<(E + 1023) / 1024, 256, 0, stream>>>(edge_attr, eemb_W, eemb_b, lin_eW, att_e,
                                                csr_se, aed, E, N);
    k_selfed<<<NB, 256, 0, stream>>>(row_ptr, aed, E, N);
    for (int i = 0; i < 3; i++) {
        k_xp<<<(N + NPB - 1) / NPB, 256, 0, stream>>>(h, lin_W + (size_t)i * HD * 256,
                                                      wsd + (size_t)i * 512,
                                                      xp, a_s, a_d, N);
        k_gat<<<(N + 3) / 4, 256, 0, stream>>>(xp, a_s, a_d, aed + (size_t)i * P4,
                                               row_ptr, csr_se,
                                               conv_b + (size_t)i * HD, h, N, E);
    }
    k_pool<<<B * PCHUNK, 256, 0, stream>>>(h, batch, pooled, N, B);
    k_mlp<<<B, 64, 0, stream>>>(u, gW, gb, pooled, batch, f1W, f1b, f2W, f2b,
                                (float*)d_out, N, B);
}